// Round 1
// 415.763 us; speedup vs baseline: 1.0597x; 1.0597x over previous
//
#include <hip/hip_runtime.h>
#include <math.h>

// Problem constants
#define BATCH 4
#define SEQ   4096
#define DMODEL 1024
#define HEADS 16
#define HDIM  64
#define CHUNK 64
#define NCHUNK 64
#define NTOK  16384          // BATCH*SEQ
#define QKVC  3072           // 3*DMODEL
#define SCALE_F 0.35355339059327373f  // 64^-0.25
#define ROPE_K 0.4152410118609203f    // log2(10000)/32

typedef unsigned short u16;
typedef _Float16 f16;
typedef __attribute__((ext_vector_type(8))) f16 f16x8;
typedef __attribute__((ext_vector_type(4))) float f32x4;

__device__ __forceinline__ u16 f2h(float f) { f16 h = (f16)f; return *(u16*)&h; }
__device__ __forceinline__ float h2f(u16 u) { f16 h = *(f16*)&u; return (float)h; }
__device__ __forceinline__ void storeC(u16* p, float v) { *p = f2h(v); }
__device__ __forceinline__ void storeC(float* p, float v) { *p = v; }

// Async global->LDS, 16B per lane. LDS dest is wave-uniform base + lane*16.
__device__ __forceinline__ void gload_lds16(const u16* g, u16* l)
{
    __builtin_amdgcn_global_load_lds(
        (const __attribute__((address_space(1))) void*)g,
        (__attribute__((address_space(3))) void*)l, 16, 0, 0);
}

// ---------------------------------------------------------------------------
// fp32 -> fp16 flat convert (n multiple of 1024)
// ---------------------------------------------------------------------------
__global__ __launch_bounds__(256)
void convert_f32_f16(const float* __restrict__ src, u16* __restrict__ dst)
{
    long i = ((long)blockIdx.x * 256 + threadIdx.x) * 4;
    float4 v = *(const float4*)(src + i);
    ushort4 o; o.x = f2h(v.x); o.y = f2h(v.y); o.z = f2h(v.z); o.w = f2h(v.w);
    *(ushort4*)(dst + i) = o;
}

// ---------------------------------------------------------------------------
// Transpose + convert: src fp32 [R][C] -> dst fp16 [C][R], dst row stride dld.
// ---------------------------------------------------------------------------
__global__ __launch_bounds__(256)
void transpose_convert(const float* __restrict__ src, int C,
                       u16* __restrict__ dst, int dld)
{
    __shared__ u16 tile[64][72];
    const int r0 = blockIdx.y * 64, c0 = blockIdx.x * 64;
    const int t = threadIdx.x;
    const int rr = t >> 4, cc4 = (t & 15) * 4;
#pragma unroll
    for (int j = 0; j < 4; ++j) {
        int r = rr + j * 16;
        float4 v = *(const float4*)(src + (long)(r0 + r) * C + c0 + cc4);
        tile[cc4 + 0][r] = f2h(v.x);
        tile[cc4 + 1][r] = f2h(v.y);
        tile[cc4 + 2][r] = f2h(v.z);
        tile[cc4 + 3][r] = f2h(v.w);
    }
    __syncthreads();
#pragma unroll
    for (int j = 0; j < 4; ++j) {
        int c = rr + j * 16;
        ushort4 o = *(ushort4*)&tile[c][cc4];
        *(ushort4*)(dst + (long)(c0 + c) * dld + r0 + cc4) = o;
    }
}

// ---------------------------------------------------------------------------
// MFMA fp16 GEMM: C[M,N] = A[M,K] @ B[K,N], B given TRANSPOSED (BT[N][K]).
// m97 structure: 128x128 tile, BK=32, global_load_lds width=16 into LINEAR
// LDS [128][32] (64B rows), 4 waves (2x2 of 64x64), 4x4 mfma 16x16x32.
// ROPE=true: fused RoPE + elu(x*SCALE)+1 epilogue on cols < 2048 (q,k).
// ---------------------------------------------------------------------------
template <typename CT, bool ROPE>
__global__ __launch_bounds__(256)
void gemm_mfma(const u16* __restrict__ A, int lda,
               const u16* __restrict__ BT, int ldbt,
               CT* __restrict__ C, int ldc, int K)
{
    __shared__ u16 As[128][32];   // linear [m][k], 64B rows (gload_lds dest)
    __shared__ u16 Bs[128][32];   // linear [n][k]

    const int tid = threadIdx.x;
    const long m0 = blockIdx.y * 128, n0 = blockIdx.x * 128;
    const int w = tid >> 6, lane = tid & 63;
    const int wm = (w >> 1) * 64, wn = (w & 1) * 64;
    const int fr = lane & 15;            // frag row (m or n)
    const int fk = (lane >> 4) * 8;      // frag k offset (quad*8)

    // Staging: wave w owns rows [w*32, w*32+32) of each tile.
    // lane -> (row = lane>>2, col16 = (lane&3)*8): matches linear LDS order.
    const int srow = w * 32 + (lane >> 2);
    const int scol = (lane & 3) * 8;
    const u16* ga = A  + (m0 + srow) * (long)lda  + scol;
    const u16* gb = BT + (n0 + srow) * (long)ldbt + scol;
    u16* const la = &As[w * 32][0];      // wave-uniform LDS bases
    u16* const lb = &Bs[w * 32][0];
    const long astep = 16 * (long)lda;
    const long bstep = 16 * (long)ldbt;

    f32x4 acc[4][4];
#pragma unroll
    for (int i = 0; i < 4; ++i)
#pragma unroll
        for (int j = 0; j < 4; ++j)
#pragma unroll
            for (int r = 0; r < 4; ++r) acc[i][j][r] = 0.0f;

    for (int kt = 0; kt < K; kt += 32) {
        gload_lds16(ga,         la);
        gload_lds16(ga + astep, la + 16 * 32);
        gload_lds16(gb,         lb);
        gload_lds16(gb + bstep, lb + 16 * 32);
        ga += 32; gb += 32;
        __syncthreads();               // compiler drains vmcnt(0) here

        f16x8 af[4], bf[4];
#pragma unroll
        for (int i = 0; i < 4; ++i) {
            af[i] = *(const f16x8*)&As[wm + i * 16 + fr][fk];
            bf[i] = *(const f16x8*)&Bs[wn + i * 16 + fr][fk];
        }
#pragma unroll
        for (int i = 0; i < 4; ++i)
#pragma unroll
            for (int j = 0; j < 4; ++j)
                acc[i][j] = __builtin_amdgcn_mfma_f32_16x16x32_f16(af[i], bf[j], acc[i][j], 0, 0, 0);
        __syncthreads();
    }

    // C/D: col = lane&15 (+16j), row = quad*4 + reg (+16i)
    const long cm = m0 + wm + (lane >> 4) * 4;
    const long cn = n0 + wn + fr;

    if (ROPE && cn < 2048) {
        // lane's 4 cols within its 64-aligned head: fr, fr+16, fr+32, fr+48.
        // rope pairs: (j0,j2) with d2=fr; (j1,j3) with d2=fr+16.
        const float invf0 = exp2f(-(float)fr * ROPE_K);
        const float invf1 = exp2f(-(float)(fr + 16) * ROPE_K);
#pragma unroll
        for (int i = 0; i < 4; ++i)
#pragma unroll
            for (int r = 0; r < 4; ++r) {
                long row = cm + i * 16 + r;
                float n = (float)(int)(row & (SEQ - 1));
                float s0, c0, s1, c1;
                __sincosf(n * invf0, &s0, &c0);
                __sincosf(n * invf1, &s1, &c1);
                float x1 = acc[i][0][r], x2 = acc[i][2][r];
                float x3 = acc[i][1][r], x4 = acc[i][3][r];
                float u1 = (x1 * c0 - x2 * s0) * SCALE_F;
                float u2 = (x1 * s0 + x2 * c0) * SCALE_F;
                float u3 = (x3 * c1 - x4 * s1) * SCALE_F;
                float u4 = (x3 * s1 + x4 * c1) * SCALE_F;
                u1 = (u1 > 0.0f) ? (u1 + 1.0f) : __expf(u1);
                u2 = (u2 > 0.0f) ? (u2 + 1.0f) : __expf(u2);
                u3 = (u3 > 0.0f) ? (u3 + 1.0f) : __expf(u3);
                u4 = (u4 > 0.0f) ? (u4 + 1.0f) : __expf(u4);
                CT* pr = C + row * ldc + cn;
                storeC(pr, u1); storeC(pr + 16, u3);
                storeC(pr + 32, u2); storeC(pr + 48, u4);
            }
    } else {
#pragma unroll
        for (int i = 0; i < 4; ++i)
#pragma unroll
            for (int j = 0; j < 4; ++j)
#pragma unroll
                for (int r = 0; r < 4; ++r)
                    storeC(&C[(cm + i * 16 + r) * ldc + cn + j * 16], acc[i][j][r]);
    }
}

// ---------------------------------------------------------------------------
// Per-(b,h,chunk): S[m][d] = sum_t V[t][m] K[t][d]  (= (K^T V)^T, fp16),
// ksum[d] = sum_t K[t][d] (fp32). MFMA 16x16x32.
// ---------------------------------------------------------------------------
__global__ __launch_bounds__(256)
void chunk_sums_mfma(const u16* __restrict__ qkv,
                     u16* __restrict__ S, float* __restrict__ ksum)
{
    __shared__ u16 Kt[64][72];   // [d][t]
    __shared__ u16 Vt[64][72];   // [m][t]

    const int blk = blockIdx.x;
    const int c = blk & 63, bh = blk >> 6;
    const int b = bh >> 4, h = bh & 15;
    const int tid = threadIdx.x;
    const long base = (long)(b * SEQ + c * CHUNK) * QKVC + h * HDIM;

#pragma unroll
    for (int j = 0; j < 4; ++j) {
        int i4 = (j * 256 + tid) * 4;
        int t = i4 >> 6, d = i4 & 63;
        const u16* src = qkv + base + (long)t * QKVC + d;
        ushort4 kk = *(const ushort4*)(src + DMODEL);
        ushort4 vv = *(const ushort4*)(src + 2 * DMODEL);
        Kt[d + 0][t] = kk.x; Kt[d + 1][t] = kk.y;
        Kt[d + 2][t] = kk.z; Kt[d + 3][t] = kk.w;
        Vt[d + 0][t] = vv.x; Vt[d + 1][t] = vv.y;
        Vt[d + 2][t] = vv.z; Vt[d + 3][t] = vv.w;
    }
    __syncthreads();

    const int w = tid >> 6, lane = tid & 63;
    const int fr = lane & 15, quad = lane >> 4;

    // D[m][d] = sum_t Vt[m][t] * K[t][d];  A = Vt, B-op layout [d][t] = Kt
    f16x8 af0 = *(const f16x8*)&Vt[w * 16 + fr][quad * 8];
    f16x8 af1 = *(const f16x8*)&Vt[w * 16 + fr][32 + quad * 8];
    f32x4 acc[4];
#pragma unroll
    for (int j = 0; j < 4; ++j)
#pragma unroll
        for (int r = 0; r < 4; ++r) acc[j][r] = 0.0f;
#pragma unroll
    for (int j = 0; j < 4; ++j) {
        f16x8 b0 = *(const f16x8*)&Kt[j * 16 + fr][quad * 8];
        f16x8 b1 = *(const f16x8*)&Kt[j * 16 + fr][32 + quad * 8];
        acc[j] = __builtin_amdgcn_mfma_f32_16x16x32_f16(af0, b0, acc[j], 0, 0, 0);
        acc[j] = __builtin_amdgcn_mfma_f32_16x16x32_f16(af1, b1, acc[j], 0, 0, 0);
    }
    const long sb = (long)blk * 4096;
    const int mrow = w * 16 + quad * 4;
#pragma unroll
    for (int j = 0; j < 4; ++j)
#pragma unroll
        for (int r = 0; r < 4; ++r)
            S[sb + (mrow + r) * 64 + j * 16 + fr] = f2h(acc[j][r]);

    if (tid < 64) {
        float s = 0.0f;
        for (int t = 0; t < 64; ++t) s += h2f(Kt[tid][t]);
        ksum[(long)blk * 64 + tid] = s;
    }
}

// ---------------------------------------------------------------------------
// Exclusive prefix scan over chunks (per bh): S (fp16) and ksum (fp32).
// ---------------------------------------------------------------------------
__global__ __launch_bounds__(256)
void scan_kernel(u16* __restrict__ S, float* __restrict__ ksum)
{
    const int blk = blockIdx.x;
    const int slice = blk & 15, bh = blk >> 4;
    const int p = slice * 256 + threadIdx.x;
    const long base = (long)bh * NCHUNK * 4096 + p;
    float acc = 0.0f;
    for (int c = 0; c < NCHUNK; ++c) {
        long idx = base + (long)c * 4096;
        float tmp = h2f(S[idx]);
        S[idx] = f2h(acc);
        acc += tmp;
    }
    if (slice == 0 && threadIdx.x < 64) {
        const long kb = (long)bh * NCHUNK * 64 + threadIdx.x;
        float ka = 0.0f;
        for (int c = 0; c < NCHUNK; ++c) {
            float t = ksum[kb + (long)c * 64];
            ksum[kb + (long)c * 64] = ka;
            ka += t;
        }
    }
}

// ---------------------------------------------------------------------------
// Per-(b,h,chunk) output via MFMA:
//   Sc = causal(Q K^T); out = Sc @ V + Q @ KV_prefix; out /= denom.
// In place over the q slice. S holds KV^T prefix ([m][d]).
// ---------------------------------------------------------------------------
__global__ __launch_bounds__(256)
void chunk_out_mfma(u16* __restrict__ qkv,
                    const u16* __restrict__ S, const float* __restrict__ ksum)
{
    __shared__ u16 Qs[64][72];    // [t][d]
    __shared__ u16 Ks[64][72];    // [s][d]  (B-op for QK^T)
    __shared__ u16 Vt[64][72];    // [m][s]  (B-op for Sc@V)
    __shared__ u16 KVt[64][72];   // [m][d]  (B-op for Q@KV)
    __shared__ u16 Sch[64][72];   // [t][s]  masked scores (A-op for Sc@V)
    __shared__ float kss[64];
    __shared__ float den[64];

    const int blk = blockIdx.x;
    const int c = blk & 63, bh = blk >> 6;
    const int b = bh >> 4, h = bh & 15;
    const int tid = threadIdx.x;
    const long base = (long)(b * SEQ + c * CHUNK) * QKVC + h * HDIM;

#pragma unroll
    for (int j = 0; j < 4; ++j) {
        int i4 = (j * 256 + tid) * 4;
        int t = i4 >> 6, d = i4 & 63;
        const u16* src = qkv + base + (long)t * QKVC + d;
        *(ushort4*)&Qs[t][d] = *(const ushort4*)(src);
        *(ushort4*)&Ks[t][d] = *(const ushort4*)(src + DMODEL);
        ushort4 vv = *(const ushort4*)(src + 2 * DMODEL);
        Vt[d + 0][t] = vv.x; Vt[d + 1][t] = vv.y;
        Vt[d + 2][t] = vv.z; Vt[d + 3][t] = vv.w;
        *(ushort4*)&KVt[t][d] = *(const ushort4*)(S + (long)blk * 4096 + i4);
    }
    if (tid < 64) kss[tid] = ksum[(long)blk * 64 + tid];
    __syncthreads();

    const int w = tid >> 6, lane = tid & 63;
    const int fr = lane & 15, quad = lane >> 4;
    const int trow = w * 16 + quad * 4;   // C-layout row base

    // --- Sc = Q K^T (wave w: rows w*16..+16) ---
    f16x8 aq0 = *(const f16x8*)&Qs[w * 16 + fr][quad * 8];
    f16x8 aq1 = *(const f16x8*)&Qs[w * 16 + fr][32 + quad * 8];
    f32x4 sc[4];
#pragma unroll
    for (int j = 0; j < 4; ++j)
#pragma unroll
        for (int r = 0; r < 4; ++r) sc[j][r] = 0.0f;
#pragma unroll
    for (int j = 0; j < 4; ++j) {
        f16x8 b0 = *(const f16x8*)&Ks[j * 16 + fr][quad * 8];
        f16x8 b1 = *(const f16x8*)&Ks[j * 16 + fr][32 + quad * 8];
        sc[j] = __builtin_amdgcn_mfma_f32_16x16x32_f16(aq0, b0, sc[j], 0, 0, 0);
        sc[j] = __builtin_amdgcn_mfma_f32_16x16x32_f16(aq1, b1, sc[j], 0, 0, 0);
    }
    // causal mask + store fp16
#pragma unroll
    for (int j = 0; j < 4; ++j)
#pragma unroll
        for (int r = 0; r < 4; ++r) {
            int t = trow + r, s = j * 16 + fr;
            Sch[t][s] = f2h(s <= t ? sc[j][r] : 0.0f);
        }
    __syncthreads();

    // --- denominators ---
    if (tid < 64) {
        float dn = 0.0f;
        for (int d = 0; d < 64; ++d) dn += h2f(Qs[tid][d]) * kss[d];
        for (int s = 0; s <= tid; ++s) dn += h2f(Sch[tid][s]);
        den[tid] = 1.0f / fmaxf(dn, 1e-6f);
    }
    __syncthreads();

    // --- out = Sch @ V + Q @ KV ---
    f16x8 as0 = *(const f16x8*)&Sch[w * 16 + fr][quad * 8];
    f16x8 as1 = *(const f16x8*)&Sch[w * 16 + fr][32 + quad * 8];
    f32x4 oc[4];
#pragma unroll
    for (int j = 0; j < 4; ++j)
#pragma unroll
        for (int r = 0; r < 4; ++r) oc[j][r] = 0.0f;
#pragma unroll
    for (int j = 0; j < 4; ++j) {
        f16x8 b0 = *(const f16x8*)&Vt[j * 16 + fr][quad * 8];
        f16x8 b1 = *(const f16x8*)&Vt[j * 16 + fr][32 + quad * 8];
        oc[j] = __builtin_amdgcn_mfma_f32_16x16x32_f16(as0, b0, oc[j], 0, 0, 0);
        oc[j] = __builtin_amdgcn_mfma_f32_16x16x32_f16(as1, b1, oc[j], 0, 0, 0);
        f16x8 k0 = *(const f16x8*)&KVt[j * 16 + fr][quad * 8];
        f16x8 k1 = *(const f16x8*)&KVt[j * 16 + fr][32 + quad * 8];
        oc[j] = __builtin_amdgcn_mfma_f32_16x16x32_f16(aq0, k0, oc[j], 0, 0, 0);
        oc[j] = __builtin_amdgcn_mfma_f32_16x16x32_f16(aq1, k1, oc[j], 0, 0, 0);
    }
    // scale by 1/denom, store in place over q slice
#pragma unroll
    for (int j = 0; j < 4; ++j)
#pragma unroll
        for (int r = 0; r < 4; ++r) {
            int t = trow + r;
            qkv[base + (long)t * QKVC + j * 16 + fr] = f2h(oc[j][r] * den[t]);
        }
}

// ---------------------------------------------------------------------------
extern "C" void kernel_launch(void* const* d_in, const int* in_sizes, int n_in,
                              void* d_out, int out_size, void* d_ws, size_t ws_size,
                              hipStream_t stream)
{
    const float* x     = (const float*)d_in[0];
    const float* w_qkv = (const float*)d_in[1];
    const float* w_out = (const float*)d_in[2];
    float* out = (float*)d_out;

    // Workspace: qkv fp16 only (100.7 MB — proven-safe footprint).
    u16* qkv = (u16*)d_ws;
    // d_out doubles as scratch before the final GEMM writes it:
    u16* xf16  = (u16*)d_out;                         // 16384*1024 fp16
    u16* wqkvT = xf16 + (size_t)NTOK * DMODEL;        // 3072*1024 fp16
    u16* S     = (u16*)d_out;                         // 64*64*4096 fp16 (alias xf16)
    float* ksum = (float*)((char*)d_out + 33554432);  // 64*64*64 fp32 (alias wqkvT)
    // w_outT lives in the dead k-slice of qkv (rows 0..1023, cols 1024..2047)
    u16* woutT = qkv + 1024;                          // [n][k], row stride 3072

    dim3 blk(256);

    // 0) conversions for GEMM1
    convert_f32_f16<<<NTOK * DMODEL / 1024, blk, 0, stream>>>(x, xf16);
    transpose_convert<<<dim3(QKVC / 64, DMODEL / 64), blk, 0, stream>>>(
        w_qkv, QKVC, wqkvT, DMODEL);

    // 1) qkv = x @ w_qkv with fused RoPE+elu on q,k cols (MFMA fp16)
    gemm_mfma<u16, true><<<dim3(QKVC / 128, NTOK / 128), blk, 0, stream>>>(
        xf16, DMODEL, wqkvT, DMODEL, qkv, QKVC, DMODEL);

    // 2) chunk-parallel linear attention (all MFMA)
    chunk_sums_mfma<<<64 * NCHUNK, blk, 0, stream>>>(qkv, S, ksum);
    scan_kernel<<<64 * 16, blk, 0, stream>>>(S, ksum);
    chunk_out_mfma<<<64 * NCHUNK, blk, 0, stream>>>(qkv, S, ksum);

    // 3) w_out transpose into dead k-slice, then out = attn @ w_out (MFMA)
    transpose_convert<<<dim3(DMODEL / 64, DMODEL / 64), blk, 0, stream>>>(
        w_out, DMODEL, woutT, QKVC);
    gemm_mfma<float, false><<<dim3(DMODEL / 128, NTOK / 128), blk, 0, stream>>>(
        qkv, QKVC, woutT, QKVC, out, DMODEL, DMODEL);
}

// Round 2
// 380.735 us; speedup vs baseline: 1.1571x; 1.0920x over previous
//
#include <hip/hip_runtime.h>
#include <math.h>

// Problem constants
#define BATCH 4
#define SEQ   4096
#define DMODEL 1024
#define HEADS 16
#define HDIM  64
#define CHUNK 64
#define NCHUNK 64
#define NTOK  16384          // BATCH*SEQ
#define QKVC  3072           // 3*DMODEL
#define SCALE_F 0.35355339059327373f  // 64^-0.25
#define ROPE_K 0.4152410118609203f    // log2(10000)/32

typedef unsigned short u16;
typedef _Float16 f16;
typedef __attribute__((ext_vector_type(8))) f16 f16x8;
typedef __attribute__((ext_vector_type(4))) float f32x4;

__device__ __forceinline__ u16 f2h(float f) { f16 h = (f16)f; return *(u16*)&h; }
__device__ __forceinline__ float h2f(u16 u) { f16 h = *(f16*)&u; return (float)h; }
__device__ __forceinline__ void storeC(u16* p, float v) { *p = f2h(v); }
__device__ __forceinline__ void storeC(float* p, float v) { *p = v; }

// Async global->LDS, 16B per lane. LDS dest is wave-uniform base + lane*16.
__device__ __forceinline__ void gload_lds16(const u16* g, u16* l)
{
    __builtin_amdgcn_global_load_lds(
        (const __attribute__((address_space(1))) void*)g,
        (__attribute__((address_space(3))) void*)l, 16, 0, 0);
}

// counted-vmcnt wait + block barrier (entering a compute phase)
#define BAR_STAGE(N) \
    asm volatile("s_waitcnt vmcnt(" #N ")" ::: "memory"); \
    __builtin_amdgcn_s_barrier(); \
    __builtin_amdgcn_sched_barrier(0);

// end-of-phase: ds_reads complete before anyone re-stages this slot
#define BAR_END() \
    asm volatile("s_waitcnt lgkmcnt(0)" ::: "memory"); \
    __builtin_amdgcn_s_barrier(); \
    __builtin_amdgcn_sched_barrier(0);

// ---------------------------------------------------------------------------
// fp32 -> fp16 flat convert (n multiple of 1024)
// ---------------------------------------------------------------------------
__global__ __launch_bounds__(256)
void convert_f32_f16(const float* __restrict__ src, u16* __restrict__ dst)
{
    long i = ((long)blockIdx.x * 256 + threadIdx.x) * 4;
    float4 v = *(const float4*)(src + i);
    ushort4 o; o.x = f2h(v.x); o.y = f2h(v.y); o.z = f2h(v.z); o.w = f2h(v.w);
    *(ushort4*)(dst + i) = o;
}

// ---------------------------------------------------------------------------
// Transpose + convert: src fp32 [R][C] -> dst fp16 [C][R], dst row stride dld.
// ---------------------------------------------------------------------------
__global__ __launch_bounds__(256)
void transpose_convert(const float* __restrict__ src, int C,
                       u16* __restrict__ dst, int dld)
{
    __shared__ u16 tile[64][72];
    const int r0 = blockIdx.y * 64, c0 = blockIdx.x * 64;
    const int t = threadIdx.x;
    const int rr = t >> 4, cc4 = (t & 15) * 4;
#pragma unroll
    for (int j = 0; j < 4; ++j) {
        int r = rr + j * 16;
        float4 v = *(const float4*)(src + (long)(r0 + r) * C + c0 + cc4);
        tile[cc4 + 0][r] = f2h(v.x);
        tile[cc4 + 1][r] = f2h(v.y);
        tile[cc4 + 2][r] = f2h(v.z);
        tile[cc4 + 3][r] = f2h(v.w);
    }
    __syncthreads();
#pragma unroll
    for (int j = 0; j < 4; ++j) {
        int c = rr + j * 16;
        ushort4 o = *(ushort4*)&tile[c][cc4];
        *(ushort4*)(dst + (long)(c0 + c) * dld + r0 + cc4) = o;
    }
}

// ---------------------------------------------------------------------------
// MFMA fp16 GEMM: C[M,N] = A[M,K] @ B[K,N], B given TRANSPOSED (BT[N][K]).
// 256x256 tile, 8 waves (2Mx4N, 128x64 per wave), ring of 4 LDS slots at
// K-half (32) granularity, prefetch depth 3 slots, counted vmcnt (never 0
// in main loop), T2 slot-XOR swizzle (both-sides), T5 setprio around MFMA.
// ROPE=true: fused RoPE + elu(x*SCALE)+1 epilogue on cols < 2048 (q,k).
// ---------------------------------------------------------------------------
template <typename CT, bool ROPE>
__global__ __launch_bounds__(512, 2)
void gemm_mfma(const u16* __restrict__ A, int lda,
               const u16* __restrict__ BT, int ldbt,
               CT* __restrict__ C, int ldc, int K)
{
    // 4 ring slots x (A 256x32 + B 256x32) u16 = 4 x 32 KB = 128 KiB
    __shared__ u16 ringA[4][256 * 32];
    __shared__ u16 ringB[4][256 * 32];

    const int tid = threadIdx.x;
    const long m0 = (long)blockIdx.y * 256, n0 = (long)blockIdx.x * 256;
    const int w = tid >> 6, lane = tid & 63;
    const int wm = w >> 2, wn = w & 3;           // 2 x 4 wave grid
    const int fr = lane & 15, quad = lane >> 4;
    // swizzled 16B-slot offset for fragment reads (u16 units):
    // slot' = quad ^ ((row>>1)&3); row = *16-aligned-base + fr
    const int sw = (quad ^ ((fr >> 1) & 3)) * 8;

    // Staging source map: one gload = 512 thr x 16B = 8 KB = 128 rows of 64B.
    // LDS chunk c = tid: row = c>>2, slot = c&3; inverse-swizzled source col.
    const int srow = tid >> 2;
    const int scol = ((tid & 3) ^ ((tid >> 3) & 3)) * 8;
    const u16* ga = A  + (m0 + srow) * (long)lda  + scol;
    const u16* gb = BT + (n0 + srow) * (long)ldbt + scol;
    const long a128 = 128 * (long)lda, b128 = 128 * (long)ldbt;

    f32x4 acc[8][4];
#pragma unroll
    for (int i = 0; i < 8; ++i)
#pragma unroll
        for (int j = 0; j < 4; ++j)
#pragma unroll
            for (int r = 0; r < 4; ++r) acc[i][j][r] = 0.0f;

    // stage one K-half slot (4 gload_lds per wave -> vmcnt += 4)
    auto STAGE = [&](int h) {
        const int s = h & 3;
        u16* la = &ringA[s][w * 512];
        u16* lb = &ringB[s][w * 512];
        const long ko = (long)h << 5;
        gload_lds16(ga + ko,        la);
        gload_lds16(ga + ko + a128, la + 4096);
        gload_lds16(gb + ko,        lb);
        gload_lds16(gb + ko + b128, lb + 4096);
    };

    // compute one K-half: 12 ds_read_b128 + 32 MFMA per wave
    auto COMPUTE = [&](int h) {
        const u16* As_ = ringA[h & 3];
        const u16* Bs_ = ringB[h & 3];
        f16x8 af[8], bf[4];
#pragma unroll
        for (int mi = 0; mi < 8; ++mi)
            af[mi] = *(const f16x8*)&As_[(wm * 128 + mi * 16 + fr) * 32 + sw];
#pragma unroll
        for (int nj = 0; nj < 4; ++nj)
            bf[nj] = *(const f16x8*)&Bs_[(wn * 64 + nj * 16 + fr) * 32 + sw];
        __builtin_amdgcn_s_setprio(1);
#pragma unroll
        for (int mi = 0; mi < 8; ++mi)
#pragma unroll
            for (int nj = 0; nj < 4; ++nj)
                acc[mi][nj] = __builtin_amdgcn_mfma_f32_16x16x32_f16(
                    af[mi], bf[nj], acc[mi][nj], 0, 0, 0);
        __builtin_amdgcn_s_setprio(0);
    };

    const int NH = K >> 5;                 // K-halves (32 for K=1024)
    STAGE(0); STAGE(1); STAGE(2);          // prologue: depth-3 prefetch
    for (int h = 0; h < NH - 3; ++h) {
        STAGE(h + 3);                      // issue-early: lands 3 phases later
        BAR_STAGE(12);                     // slots h+1..h+3 in flight; h landed
        COMPUTE(h);
        BAR_END();                         // reads done before slot reuse
    }
    BAR_STAGE(8);  COMPUTE(NH - 3);        // epilogue drain 8 -> 4 -> 0
    BAR_STAGE(4);  COMPUTE(NH - 2);
    BAR_STAGE(0);  COMPUTE(NH - 1);

    // C/D: col = lane&15 (+16*nj), row = quad*4 + r (+16*mi)
    const long cm = m0 + wm * 128 + quad * 4;
    const long cn = n0 + wn * 64 + fr;

    if (ROPE && cn < 2048) {
        // lane's 4 cols within its 64-aligned head: fr, fr+16, fr+32, fr+48.
        // rope pairs: (nj0,nj2) with d2=fr; (nj1,nj3) with d2=fr+16.
        const float invf0 = exp2f(-(float)fr * ROPE_K);
        const float invf1 = exp2f(-(float)(fr + 16) * ROPE_K);
#pragma unroll
        for (int mi = 0; mi < 8; ++mi)
#pragma unroll
            for (int r = 0; r < 4; ++r) {
                long row = cm + mi * 16 + r;
                float n = (float)(int)(row & (SEQ - 1));
                float s0, c0, s1, c1;
                __sincosf(n * invf0, &s0, &c0);
                __sincosf(n * invf1, &s1, &c1);
                float x1 = acc[mi][0][r], x2 = acc[mi][2][r];
                float x3 = acc[mi][1][r], x4 = acc[mi][3][r];
                float u1 = (x1 * c0 - x2 * s0) * SCALE_F;
                float u2 = (x1 * s0 + x2 * c0) * SCALE_F;
                float u3 = (x3 * c1 - x4 * s1) * SCALE_F;
                float u4 = (x3 * s1 + x4 * c1) * SCALE_F;
                u1 = (u1 > 0.0f) ? (u1 + 1.0f) : __expf(u1);
                u2 = (u2 > 0.0f) ? (u2 + 1.0f) : __expf(u2);
                u3 = (u3 > 0.0f) ? (u3 + 1.0f) : __expf(u3);
                u4 = (u4 > 0.0f) ? (u4 + 1.0f) : __expf(u4);
                CT* pr = C + row * ldc + cn;
                storeC(pr, u1); storeC(pr + 16, u3);
                storeC(pr + 32, u2); storeC(pr + 48, u4);
            }
    } else {
#pragma unroll
        for (int mi = 0; mi < 8; ++mi)
#pragma unroll
            for (int nj = 0; nj < 4; ++nj)
#pragma unroll
                for (int r = 0; r < 4; ++r)
                    storeC(&C[(cm + mi * 16 + r) * ldc + cn + nj * 16], acc[mi][nj][r]);
    }
}

// ---------------------------------------------------------------------------
// Per-(b,h,chunk): S[m][d] = sum_t V[t][m] K[t][d]  (= (K^T V)^T, fp16),
// ksum[d] = sum_t K[t][d] (fp32). MFMA 16x16x32.
// ---------------------------------------------------------------------------
__global__ __launch_bounds__(256)
void chunk_sums_mfma(const u16* __restrict__ qkv,
                     u16* __restrict__ S, float* __restrict__ ksum)
{
    __shared__ u16 Kt[64][72];   // [d][t]
    __shared__ u16 Vt[64][72];   // [m][t]

    const int blk = blockIdx.x;
    const int c = blk & 63, bh = blk >> 6;
    const int b = bh >> 4, h = bh & 15;
    const int tid = threadIdx.x;
    const long base = (long)(b * SEQ + c * CHUNK) * QKVC + h * HDIM;

#pragma unroll
    for (int j = 0; j < 4; ++j) {
        int i4 = (j * 256 + tid) * 4;
        int t = i4 >> 6, d = i4 & 63;
        const u16* src = qkv + base + (long)t * QKVC + d;
        ushort4 kk = *(const ushort4*)(src + DMODEL);
        ushort4 vv = *(const ushort4*)(src + 2 * DMODEL);
        Kt[d + 0][t] = kk.x; Kt[d + 1][t] = kk.y;
        Kt[d + 2][t] = kk.z; Kt[d + 3][t] = kk.w;
        Vt[d + 0][t] = vv.x; Vt[d + 1][t] = vv.y;
        Vt[d + 2][t] = vv.z; Vt[d + 3][t] = vv.w;
    }
    __syncthreads();

    const int w = tid >> 6, lane = tid & 63;
    const int fr = lane & 15, quad = lane >> 4;

    // D[m][d] = sum_t Vt[m][t] * K[t][d];  A = Vt, B-op layout [d][t] = Kt
    f16x8 af0 = *(const f16x8*)&Vt[w * 16 + fr][quad * 8];
    f16x8 af1 = *(const f16x8*)&Vt[w * 16 + fr][32 + quad * 8];
    f32x4 acc[4];
#pragma unroll
    for (int j = 0; j < 4; ++j)
#pragma unroll
        for (int r = 0; r < 4; ++r) acc[j][r] = 0.0f;
#pragma unroll
    for (int j = 0; j < 4; ++j) {
        f16x8 b0 = *(const f16x8*)&Kt[j * 16 + fr][quad * 8];
        f16x8 b1 = *(const f16x8*)&Kt[j * 16 + fr][32 + quad * 8];
        acc[j] = __builtin_amdgcn_mfma_f32_16x16x32_f16(af0, b0, acc[j], 0, 0, 0);
        acc[j] = __builtin_amdgcn_mfma_f32_16x16x32_f16(af1, b1, acc[j], 0, 0, 0);
    }
    const long sb = (long)blk * 4096;
    const int mrow = w * 16 + quad * 4;
#pragma unroll
    for (int j = 0; j < 4; ++j)
#pragma unroll
        for (int r = 0; r < 4; ++r)
            S[sb + (mrow + r) * 64 + j * 16 + fr] = f2h(acc[j][r]);

    if (tid < 64) {
        float s = 0.0f;
        for (int t = 0; t < 64; ++t) s += h2f(Kt[tid][t]);
        ksum[(long)blk * 64 + tid] = s;
    }
}

// ---------------------------------------------------------------------------
// Exclusive prefix scan over chunks (per bh): S (fp16) and ksum (fp32).
// ---------------------------------------------------------------------------
__global__ __launch_bounds__(256)
void scan_kernel(u16* __restrict__ S, float* __restrict__ ksum)
{
    const int blk = blockIdx.x;
    const int slice = blk & 15, bh = blk >> 4;
    const int p = slice * 256 + threadIdx.x;
    const long base = (long)bh * NCHUNK * 4096 + p;
    float acc = 0.0f;
    for (int c = 0; c < NCHUNK; ++c) {
        long idx = base + (long)c * 4096;
        float tmp = h2f(S[idx]);
        S[idx] = f2h(acc);
        acc += tmp;
    }
    if (slice == 0 && threadIdx.x < 64) {
        const long kb = (long)bh * NCHUNK * 64 + threadIdx.x;
        float ka = 0.0f;
        for (int c = 0; c < NCHUNK; ++c) {
            float t = ksum[kb + (long)c * 64];
            ksum[kb + (long)c * 64] = ka;
            ka += t;
        }
    }
}

// ---------------------------------------------------------------------------
// Per-(b,h,chunk) output via MFMA:
//   Sc = causal(Q K^T); out = Sc @ V + Q @ KV_prefix; out /= denom.
// In place over the q slice. S holds KV^T prefix ([m][d]).
// ---------------------------------------------------------------------------
__global__ __launch_bounds__(256)
void chunk_out_mfma(u16* __restrict__ qkv,
                    const u16* __restrict__ S, const float* __restrict__ ksum)
{
    __shared__ u16 Qs[64][72];    // [t][d]
    __shared__ u16 Ks[64][72];    // [s][d]  (B-op for QK^T)
    __shared__ u16 Vt[64][72];    // [m][s]  (B-op for Sc@V)
    __shared__ u16 KVt[64][72];   // [m][d]  (B-op for Q@KV)
    __shared__ u16 Sch[64][72];   // [t][s]  masked scores (A-op for Sc@V)
    __shared__ float kss[64];
    __shared__ float den[64];

    const int blk = blockIdx.x;
    const int c = blk & 63, bh = blk >> 6;
    const int b = bh >> 4, h = bh & 15;
    const int tid = threadIdx.x;
    const long base = (long)(b * SEQ + c * CHUNK) * QKVC + h * HDIM;

#pragma unroll
    for (int j = 0; j < 4; ++j) {
        int i4 = (j * 256 + tid) * 4;
        int t = i4 >> 6, d = i4 & 63;
        const u16* src = qkv + base + (long)t * QKVC + d;
        *(ushort4*)&Qs[t][d] = *(const ushort4*)(src);
        *(ushort4*)&Ks[t][d] = *(const ushort4*)(src + DMODEL);
        ushort4 vv = *(const ushort4*)(src + 2 * DMODEL);
        Vt[d + 0][t] = vv.x; Vt[d + 1][t] = vv.y;
        Vt[d + 2][t] = vv.z; Vt[d + 3][t] = vv.w;
        *(ushort4*)&KVt[t][d] = *(const ushort4*)(S + (long)blk * 4096 + i4);
    }
    if (tid < 64) kss[tid] = ksum[(long)blk * 64 + tid];
    __syncthreads();

    const int w = tid >> 6, lane = tid & 63;
    const int fr = lane & 15, quad = lane >> 4;
    const int trow = w * 16 + quad * 4;   // C-layout row base

    // --- Sc = Q K^T (wave w: rows w*16..+16) ---
    f16x8 aq0 = *(const f16x8*)&Qs[w * 16 + fr][quad * 8];
    f16x8 aq1 = *(const f16x8*)&Qs[w * 16 + fr][32 + quad * 8];
    f32x4 sc[4];
#pragma unroll
    for (int j = 0; j < 4; ++j)
#pragma unroll
        for (int r = 0; r < 4; ++r) sc[j][r] = 0.0f;
#pragma unroll
    for (int j = 0; j < 4; ++j) {
        f16x8 b0 = *(const f16x8*)&Ks[j * 16 + fr][quad * 8];
        f16x8 b1 = *(const f16x8*)&Ks[j * 16 + fr][32 + quad * 8];
        sc[j] = __builtin_amdgcn_mfma_f32_16x16x32_f16(aq0, b0, sc[j], 0, 0, 0);
        sc[j] = __builtin_amdgcn_mfma_f32_16x16x32_f16(aq1, b1, sc[j], 0, 0, 0);
    }
    // causal mask + store fp16
#pragma unroll
    for (int j = 0; j < 4; ++j)
#pragma unroll
        for (int r = 0; r < 4; ++r) {
            int t = trow + r, s = j * 16 + fr;
            Sch[t][s] = f2h(s <= t ? sc[j][r] : 0.0f);
        }
    __syncthreads();

    // --- denominators ---
    if (tid < 64) {
        float dn = 0.0f;
        for (int d = 0; d < 64; ++d) dn += h2f(Qs[tid][d]) * kss[d];
        for (int s = 0; s <= tid; ++s) dn += h2f(Sch[tid][s]);
        den[tid] = 1.0f / fmaxf(dn, 1e-6f);
    }
    __syncthreads();

    // --- out = Sch @ V + Q @ KV ---
    f16x8 as0 = *(const f16x8*)&Sch[w * 16 + fr][quad * 8];
    f16x8 as1 = *(const f16x8*)&Sch[w * 16 + fr][32 + quad * 8];
    f32x4 oc[4];
#pragma unroll
    for (int j = 0; j < 4; ++j)
#pragma unroll
        for (int r = 0; r < 4; ++r) oc[j][r] = 0.0f;
#pragma unroll
    for (int j = 0; j < 4; ++j) {
        f16x8 b0 = *(const f16x8*)&Vt[j * 16 + fr][quad * 8];
        f16x8 b1 = *(const f16x8*)&Vt[j * 16 + fr][32 + quad * 8];
        oc[j] = __builtin_amdgcn_mfma_f32_16x16x32_f16(as0, b0, oc[j], 0, 0, 0);
        oc[j] = __builtin_amdgcn_mfma_f32_16x16x32_f16(as1, b1, oc[j], 0, 0, 0);
        f16x8 k0 = *(const f16x8*)&KVt[j * 16 + fr][quad * 8];
        f16x8 k1 = *(const f16x8*)&KVt[j * 16 + fr][32 + quad * 8];
        oc[j] = __builtin_amdgcn_mfma_f32_16x16x32_f16(aq0, k0, oc[j], 0, 0, 0);
        oc[j] = __builtin_amdgcn_mfma_f32_16x16x32_f16(aq1, k1, oc[j], 0, 0, 0);
    }
    // scale by 1/denom, store in place over q slice
#pragma unroll
    for (int j = 0; j < 4; ++j)
#pragma unroll
        for (int r = 0; r < 4; ++r) {
            int t = trow + r;
            qkv[base + (long)t * QKVC + j * 16 + fr] = f2h(oc[j][r] * den[t]);
        }
}

// ---------------------------------------------------------------------------
extern "C" void kernel_launch(void* const* d_in, const int* in_sizes, int n_in,
                              void* d_out, int out_size, void* d_ws, size_t ws_size,
                              hipStream_t stream)
{
    const float* x     = (const float*)d_in[0];
    const float* w_qkv = (const float*)d_in[1];
    const float* w_out = (const float*)d_in[2];
    float* out = (float*)d_out;

    // Workspace: qkv fp16 only (100.7 MB — proven-safe footprint).
    u16* qkv = (u16*)d_ws;
    // d_out doubles as scratch before the final GEMM writes it:
    u16* xf16  = (u16*)d_out;                         // 16384*1024 fp16
    u16* wqkvT = xf16 + (size_t)NTOK * DMODEL;        // 3072*1024 fp16
    u16* S     = (u16*)d_out;                         // 64*64*4096 fp16 (alias xf16)
    float* ksum = (float*)((char*)d_out + 33554432);  // 64*64*64 fp32 (alias wqkvT)
    // w_outT lives in the dead k-slice of qkv (rows 0..1023, cols 1024..2047)
    u16* woutT = qkv + 1024;                          // [n][k], row stride 3072

    dim3 blk(256);
    dim3 gblk(512);

    // 0) conversions for GEMM1
    convert_f32_f16<<<NTOK * DMODEL / 1024, blk, 0, stream>>>(x, xf16);
    transpose_convert<<<dim3(QKVC / 64, DMODEL / 64), blk, 0, stream>>>(
        w_qkv, QKVC, wqkvT, DMODEL);

    // 1) qkv = x @ w_qkv with fused RoPE+elu on q,k cols (MFMA fp16, 256² ring)
    gemm_mfma<u16, true><<<dim3(QKVC / 256, NTOK / 256), gblk, 0, stream>>>(
        xf16, DMODEL, wqkvT, DMODEL, qkv, QKVC, DMODEL);

    // 2) chunk-parallel linear attention (all MFMA)
    chunk_sums_mfma<<<64 * NCHUNK, blk, 0, stream>>>(qkv, S, ksum);
    scan_kernel<<<64 * 16, blk, 0, stream>>>(S, ksum);
    chunk_out_mfma<<<64 * NCHUNK, blk, 0, stream>>>(qkv, S, ksum);

    // 3) w_out transpose into dead k-slice, then out = attn @ w_out (MFMA)
    transpose_convert<<<dim3(DMODEL / 64, DMODEL / 64), blk, 0, stream>>>(
        w_out, DMODEL, woutT, QKVC);
    gemm_mfma<float, false><<<dim3(DMODEL / 256, NTOK / 256), gblk, 0, stream>>>(
        qkv, QKVC, woutT, QKVC, out, DMODEL, DMODEL);
}

// Round 3
// 356.589 us; speedup vs baseline: 1.2355x; 1.0677x over previous
//
#include <hip/hip_runtime.h>
#include <math.h>

// Problem constants
#define BATCH 4
#define SEQ   4096
#define DMODEL 1024
#define HEADS 16
#define HDIM  64
#define CHUNK 64
#define NCHUNK 64
#define NTOK  16384          // BATCH*SEQ
#define QKVC  3072           // 3*DMODEL
#define SCALE_F 0.35355339059327373f  // 64^-0.25
#define ROPE_K 0.4152410118609203f    // log2(10000)/32

typedef unsigned short u16;
typedef _Float16 f16;
typedef __attribute__((ext_vector_type(8))) f16 f16x8;
typedef __attribute__((ext_vector_type(4))) float f32x4;

__device__ __forceinline__ u16 f2h(float f) { f16 h = (f16)f; return *(u16*)&h; }
__device__ __forceinline__ float h2f(u16 u) { f16 h = *(f16*)&u; return (float)h; }
__device__ __forceinline__ void storeC(u16* p, float v) { *p = f2h(v); }
__device__ __forceinline__ void storeC(float* p, float v) { *p = v; }

// Async global->LDS, 16B per lane. LDS dest is wave-uniform base + lane*16.
__device__ __forceinline__ void gload_lds16(const u16* g, u16* l)
{
    __builtin_amdgcn_global_load_lds(
        (const __attribute__((address_space(1))) void*)g,
        (__attribute__((address_space(3))) void*)l, 16, 0, 0);
}

// ---------------------------------------------------------------------------
// fp32 -> fp16 flat convert (n multiple of 1024)
// ---------------------------------------------------------------------------
__global__ __launch_bounds__(256)
void convert_f32_f16(const float* __restrict__ src, u16* __restrict__ dst)
{
    long i = ((long)blockIdx.x * 256 + threadIdx.x) * 4;
    float4 v = *(const float4*)(src + i);
    ushort4 o; o.x = f2h(v.x); o.y = f2h(v.y); o.z = f2h(v.z); o.w = f2h(v.w);
    *(ushort4*)(dst + i) = o;
}

// ---------------------------------------------------------------------------
// Transpose + convert: src fp32 [R][C] -> dst fp16 [C][R], dst row stride dld.
// ---------------------------------------------------------------------------
__global__ __launch_bounds__(256)
void transpose_convert(const float* __restrict__ src, int C,
                       u16* __restrict__ dst, int dld)
{
    __shared__ u16 tile[64][72];
    const int r0 = blockIdx.y * 64, c0 = blockIdx.x * 64;
    const int t = threadIdx.x;
    const int rr = t >> 4, cc4 = (t & 15) * 4;
#pragma unroll
    for (int j = 0; j < 4; ++j) {
        int r = rr + j * 16;
        float4 v = *(const float4*)(src + (long)(r0 + r) * C + c0 + cc4);
        tile[cc4 + 0][r] = f2h(v.x);
        tile[cc4 + 1][r] = f2h(v.y);
        tile[cc4 + 2][r] = f2h(v.z);
        tile[cc4 + 3][r] = f2h(v.w);
    }
    __syncthreads();
#pragma unroll
    for (int j = 0; j < 4; ++j) {
        int c = rr + j * 16;
        ushort4 o = *(ushort4*)&tile[c][cc4];
        *(ushort4*)(dst + (long)(c0 + c) * dld + r0 + cc4) = o;
    }
}

// ---------------------------------------------------------------------------
// MFMA fp16 GEMM: C[M,N] = A[M,K] @ B[K,N], B given TRANSPOSED (BT[N][K]).
// 256x256 tile, 8 waves (2Mx4N, 128x64/wave), ring of 4 K=32 slots, depth-3
// prefetch. ONE barrier + ONE counted vmcnt + ONE lgkmcnt per K-half:
//   [MFMA1(h) | reads(h+1)+stageA | MFMA0(h+1) | af1-reads+stageB |
//    vmcnt(8); lgkmcnt(0); s_barrier]
// Reads issued at window top (latency hidden under MFMA / barrier skew);
// hazards closed by construction (see comments). T2 slot-XOR swizzle
// (bank-conflict-free, measured 0), T5 setprio around each MFMA cluster.
// ROPE=true: fused RoPE + elu(x*SCALE)+1 epilogue on cols < 2048 (q,k).
// ---------------------------------------------------------------------------
template <typename CT, bool ROPE>
__global__ __launch_bounds__(512, 2)
void gemm_mfma(const u16* __restrict__ A, int lda,
               const u16* __restrict__ BT, int ldbt,
               CT* __restrict__ C, int ldc, int K)
{
    // 4 ring slots x (A 256x32 + B 256x32) u16 = 4 x 32 KB = 128 KiB
    __shared__ u16 ringA[4][256 * 32];
    __shared__ u16 ringB[4][256 * 32];

    const int tid = threadIdx.x;
    const long m0 = (long)blockIdx.y * 256, n0 = (long)blockIdx.x * 256;
    const int w = tid >> 6, lane = tid & 63;
    const int wm = w >> 2, wn = w & 3;           // 2 x 4 wave grid
    const int fr = lane & 15, quad = lane >> 4;
    // swizzled 16B-slot offset for fragment reads (u16 units):
    // slot' = quad ^ ((row>>1)&3); row within 16-aligned base -> fr
    const int sw = (quad ^ ((fr >> 1) & 3)) * 8;

    // Staging source map: one gload = 512 thr x 16B = 8 KB = 128 rows of 64B.
    // LDS chunk c = tid: row = c>>2, slot = c&3; inverse-swizzled source col.
    const int srow = tid >> 2;
    const int scol = ((tid & 3) ^ ((tid >> 3) & 3)) * 8;
    const u16* ga = A  + (m0 + srow) * (long)lda  + scol;
    const u16* gb = BT + (n0 + srow) * (long)ldbt + scol;
    const long a128 = 128 * (long)lda, b128 = 128 * (long)ldbt;

    f32x4 acc[8][4];
#pragma unroll
    for (int i = 0; i < 8; ++i)
#pragma unroll
        for (int j = 0; j < 4; ++j)
#pragma unroll
            for (int r = 0; r < 4; ++r) acc[i][j][r] = 0.0f;

    // stage halves of one K-slot (2 gloads each -> vmcnt += 2)
    auto STAGE_A = [&](int h) {
        u16* la = &ringA[h & 3][w * 512];
        const long ko = (long)h << 5;
        gload_lds16(ga + ko,        la);
        gload_lds16(ga + ko + a128, la + 4096);
    };
    auto STAGE_B = [&](int h) {
        u16* lb = &ringB[h & 3][w * 512];
        const long ko = (long)h << 5;
        gload_lds16(gb + ko,        lb);
        gload_lds16(gb + ko + b128, lb + 4096);
    };

    // prologue: stage slots 0..2 (12 gloads), validate slot 0
    STAGE_A(0); STAGE_B(0);
    STAGE_A(1); STAGE_B(1);
    STAGE_A(2); STAGE_B(2);
    asm volatile("s_waitcnt vmcnt(8)" ::: "memory");   // slot 0 landed (mine)
    __builtin_amdgcn_s_barrier();                      // slot 0 valid block-wide

    const int NH = K >> 5;                             // 32 for K=1024
    for (int h = 0; h < NH; ++h) {
        const u16* As_ = ringA[h & 3];
        const u16* Bs_ = ringB[h & 3];
        f16x8 af0[4], af1[4], bf[4];

        // --- window top: reads for this slot + stage A-half of h+3 ---
#pragma unroll
        for (int mi = 0; mi < 4; ++mi)
            af0[mi] = *(const f16x8*)&As_[(wm * 128 + mi * 16 + fr) * 32 + sw];
#pragma unroll
        for (int nj = 0; nj < 4; ++nj)
            bf[nj] = *(const f16x8*)&Bs_[(wn * 64 + nj * 16 + fr) * 32 + sw];
        if (h < NH - 3) STAGE_A(h + 3);   // writes slot (h-1)&3: reads drained at B(h-1)

        // --- MFMA cluster 0 (mi 0..3) ---
        __builtin_amdgcn_s_setprio(1);
#pragma unroll
        for (int mi = 0; mi < 4; ++mi)
#pragma unroll
            for (int nj = 0; nj < 4; ++nj)
                acc[mi][nj] = __builtin_amdgcn_mfma_f32_16x16x32_f16(
                    af0[mi], bf[nj], acc[mi][nj], 0, 0, 0);
        __builtin_amdgcn_s_setprio(0);

        // --- second half reads + stage B-half of h+3 ---
#pragma unroll
        for (int mi = 0; mi < 4; ++mi)
            af1[mi] = *(const f16x8*)&As_[(wm * 128 + (mi + 4) * 16 + fr) * 32 + sw];
        if (h < NH - 3) STAGE_B(h + 3);

        // --- single sync point per slot: validate slot h+1, fence reads ---
        if (h <= NH - 4) {
            asm volatile("s_waitcnt vmcnt(8)" ::: "memory");   // slot h+1 landed
        } else if (h == NH - 3) {
            asm volatile("s_waitcnt vmcnt(4)" ::: "memory");
        } else if (h == NH - 2) {
            asm volatile("s_waitcnt vmcnt(0)" ::: "memory");
        }
        if (h < NH - 1) {
            asm volatile("s_waitcnt lgkmcnt(0)" ::: "memory"); // my slot-h reads done
            __builtin_amdgcn_s_barrier();                      // block-wide rendezvous
        }

        // --- MFMA cluster 1 (mi 4..7, operands pre-drained) ---
        __builtin_amdgcn_s_setprio(1);
#pragma unroll
        for (int mi = 0; mi < 4; ++mi)
#pragma unroll
            for (int nj = 0; nj < 4; ++nj)
                acc[mi + 4][nj] = __builtin_amdgcn_mfma_f32_16x16x32_f16(
                    af1[mi], bf[nj], acc[mi + 4][nj], 0, 0, 0);
        __builtin_amdgcn_s_setprio(0);
    }

    // C/D: col = lane&15 (+16*nj), row = quad*4 + r (+16*mi)
    const long cm = m0 + wm * 128 + quad * 4;
    const long cn = n0 + wn * 64 + fr;

    if (ROPE && cn < 2048) {
        // lane's 4 cols within its 64-aligned head: fr, fr+16, fr+32, fr+48.
        // rope pairs: (nj0,nj2) with d2=fr; (nj1,nj3) with d2=fr+16.
        const float invf0 = exp2f(-(float)fr * ROPE_K);
        const float invf1 = exp2f(-(float)(fr + 16) * ROPE_K);
#pragma unroll
        for (int mi = 0; mi < 8; ++mi)
#pragma unroll
            for (int r = 0; r < 4; ++r) {
                long row = cm + mi * 16 + r;
                float n = (float)(int)(row & (SEQ - 1));
                float s0, c0, s1, c1;
                __sincosf(n * invf0, &s0, &c0);
                __sincosf(n * invf1, &s1, &c1);
                float x1 = acc[mi][0][r], x2 = acc[mi][2][r];
                float x3 = acc[mi][1][r], x4 = acc[mi][3][r];
                float u1 = (x1 * c0 - x2 * s0) * SCALE_F;
                float u2 = (x1 * s0 + x2 * c0) * SCALE_F;
                float u3 = (x3 * c1 - x4 * s1) * SCALE_F;
                float u4 = (x3 * s1 + x4 * c1) * SCALE_F;
                u1 = (u1 > 0.0f) ? (u1 + 1.0f) : __expf(u1);
                u2 = (u2 > 0.0f) ? (u2 + 1.0f) : __expf(u2);
                u3 = (u3 > 0.0f) ? (u3 + 1.0f) : __expf(u3);
                u4 = (u4 > 0.0f) ? (u4 + 1.0f) : __expf(u4);
                CT* pr = C + row * ldc + cn;
                storeC(pr, u1); storeC(pr + 16, u3);
                storeC(pr + 32, u2); storeC(pr + 48, u4);
            }
    } else {
#pragma unroll
        for (int mi = 0; mi < 8; ++mi)
#pragma unroll
            for (int nj = 0; nj < 4; ++nj)
#pragma unroll
                for (int r = 0; r < 4; ++r)
                    storeC(&C[(cm + mi * 16 + r) * ldc + cn + nj * 16], acc[mi][nj][r]);
    }
}

// ---------------------------------------------------------------------------
// Per-(b,h,chunk): S[m][d] = sum_t V[t][m] K[t][d]  (= (K^T V)^T, fp16),
// ksum[d] = sum_t K[t][d] (fp32). MFMA 16x16x32.
// ---------------------------------------------------------------------------
__global__ __launch_bounds__(256)
void chunk_sums_mfma(const u16* __restrict__ qkv,
                     u16* __restrict__ S, float* __restrict__ ksum)
{
    __shared__ u16 Kt[64][72];   // [d][t]
    __shared__ u16 Vt[64][72];   // [m][t]

    const int blk = blockIdx.x;
    const int c = blk & 63, bh = blk >> 6;
    const int b = bh >> 4, h = bh & 15;
    const int tid = threadIdx.x;
    const long base = (long)(b * SEQ + c * CHUNK) * QKVC + h * HDIM;

#pragma unroll
    for (int j = 0; j < 4; ++j) {
        int i4 = (j * 256 + tid) * 4;
        int t = i4 >> 6, d = i4 & 63;
        const u16* src = qkv + base + (long)t * QKVC + d;
        ushort4 kk = *(const ushort4*)(src + DMODEL);
        ushort4 vv = *(const ushort4*)(src + 2 * DMODEL);
        Kt[d + 0][t] = kk.x; Kt[d + 1][t] = kk.y;
        Kt[d + 2][t] = kk.z; Kt[d + 3][t] = kk.w;
        Vt[d + 0][t] = vv.x; Vt[d + 1][t] = vv.y;
        Vt[d + 2][t] = vv.z; Vt[d + 3][t] = vv.w;
    }
    __syncthreads();

    const int w = tid >> 6, lane = tid & 63;
    const int fr = lane & 15, quad = lane >> 4;

    // D[m][d] = sum_t Vt[m][t] * K[t][d];  A = Vt, B-op layout [d][t] = Kt
    f16x8 af0 = *(const f16x8*)&Vt[w * 16 + fr][quad * 8];
    f16x8 af1 = *(const f16x8*)&Vt[w * 16 + fr][32 + quad * 8];
    f32x4 acc[4];
#pragma unroll
    for (int j = 0; j < 4; ++j)
#pragma unroll
        for (int r = 0; r < 4; ++r) acc[j][r] = 0.0f;
#pragma unroll
    for (int j = 0; j < 4; ++j) {
        f16x8 b0 = *(const f16x8*)&Kt[j * 16 + fr][quad * 8];
        f16x8 b1 = *(const f16x8*)&Kt[j * 16 + fr][32 + quad * 8];
        acc[j] = __builtin_amdgcn_mfma_f32_16x16x32_f16(af0, b0, acc[j], 0, 0, 0);
        acc[j] = __builtin_amdgcn_mfma_f32_16x16x32_f16(af1, b1, acc[j], 0, 0, 0);
    }
    const long sb = (long)blk * 4096;
    const int mrow = w * 16 + quad * 4;
#pragma unroll
    for (int j = 0; j < 4; ++j)
#pragma unroll
        for (int r = 0; r < 4; ++r)
            S[sb + (mrow + r) * 64 + j * 16 + fr] = f2h(acc[j][r]);

    if (tid < 64) {
        float s = 0.0f;
        for (int t = 0; t < 64; ++t) s += h2f(Kt[tid][t]);
        ksum[(long)blk * 64 + tid] = s;
    }
}

// ---------------------------------------------------------------------------
// Exclusive prefix scan over chunks (per bh): S (fp16) and ksum (fp32).
// ---------------------------------------------------------------------------
__global__ __launch_bounds__(256)
void scan_kernel(u16* __restrict__ S, float* __restrict__ ksum)
{
    const int blk = blockIdx.x;
    const int slice = blk & 15, bh = blk >> 4;
    const int p = slice * 256 + threadIdx.x;
    const long base = (long)bh * NCHUNK * 4096 + p;
    float acc = 0.0f;
    for (int c = 0; c < NCHUNK; ++c) {
        long idx = base + (long)c * 4096;
        float tmp = h2f(S[idx]);
        S[idx] = f2h(acc);
        acc += tmp;
    }
    if (slice == 0 && threadIdx.x < 64) {
        const long kb = (long)bh * NCHUNK * 64 + threadIdx.x;
        float ka = 0.0f;
        for (int c = 0; c < NCHUNK; ++c) {
            float t = ksum[kb + (long)c * 64];
            ksum[kb + (long)c * 64] = ka;
            ka += t;
        }
    }
}

// ---------------------------------------------------------------------------
// Per-(b,h,chunk) output via MFMA:
//   Sc = causal(Q K^T); out = Sc @ V + Q @ KV_prefix; out /= denom.
// In place over the q slice. S holds KV^T prefix ([m][d]).
// ---------------------------------------------------------------------------
__global__ __launch_bounds__(256)
void chunk_out_mfma(u16* __restrict__ qkv,
                    const u16* __restrict__ S, const float* __restrict__ ksum)
{
    __shared__ u16 Qs[64][72];    // [t][d]
    __shared__ u16 Ks[64][72];    // [s][d]  (B-op for QK^T)
    __shared__ u16 Vt[64][72];    // [m][s]  (B-op for Sc@V)
    __shared__ u16 KVt[64][72];   // [m][d]  (B-op for Q@KV)
    __shared__ u16 Sch[64][72];   // [t][s]  masked scores (A-op for Sc@V)
    __shared__ float kss[64];
    __shared__ float den[64];

    const int blk = blockIdx.x;
    const int c = blk & 63, bh = blk >> 6;
    const int b = bh >> 4, h = bh & 15;
    const int tid = threadIdx.x;
    const long base = (long)(b * SEQ + c * CHUNK) * QKVC + h * HDIM;

#pragma unroll
    for (int j = 0; j < 4; ++j) {
        int i4 = (j * 256 + tid) * 4;
        int t = i4 >> 6, d = i4 & 63;
        const u16* src = qkv + base + (long)t * QKVC + d;
        *(ushort4*)&Qs[t][d] = *(const ushort4*)(src);
        *(ushort4*)&Ks[t][d] = *(const ushort4*)(src + DMODEL);
        ushort4 vv = *(const ushort4*)(src + 2 * DMODEL);
        Vt[d + 0][t] = vv.x; Vt[d + 1][t] = vv.y;
        Vt[d + 2][t] = vv.z; Vt[d + 3][t] = vv.w;
        *(ushort4*)&KVt[t][d] = *(const ushort4*)(S + (long)blk * 4096 + i4);
    }
    if (tid < 64) kss[tid] = ksum[(long)blk * 64 + tid];
    __syncthreads();

    const int w = tid >> 6, lane = tid & 63;
    const int fr = lane & 15, quad = lane >> 4;
    const int trow = w * 16 + quad * 4;   // C-layout row base

    // --- Sc = Q K^T (wave w: rows w*16..+16) ---
    f16x8 aq0 = *(const f16x8*)&Qs[w * 16 + fr][quad * 8];
    f16x8 aq1 = *(const f16x8*)&Qs[w * 16 + fr][32 + quad * 8];
    f32x4 sc[4];
#pragma unroll
    for (int j = 0; j < 4; ++j)
#pragma unroll
        for (int r = 0; r < 4; ++r) sc[j][r] = 0.0f;
#pragma unroll
    for (int j = 0; j < 4; ++j) {
        f16x8 b0 = *(const f16x8*)&Ks[j * 16 + fr][quad * 8];
        f16x8 b1 = *(const f16x8*)&Ks[j * 16 + fr][32 + quad * 8];
        sc[j] = __builtin_amdgcn_mfma_f32_16x16x32_f16(aq0, b0, sc[j], 0, 0, 0);
        sc[j] = __builtin_amdgcn_mfma_f32_16x16x32_f16(aq1, b1, sc[j], 0, 0, 0);
    }
    // causal mask + store fp16
#pragma unroll
    for (int j = 0; j < 4; ++j)
#pragma unroll
        for (int r = 0; r < 4; ++r) {
            int t = trow + r, s = j * 16 + fr;
            Sch[t][s] = f2h(s <= t ? sc[j][r] : 0.0f);
        }
    __syncthreads();

    // --- denominators ---
    if (tid < 64) {
        float dn = 0.0f;
        for (int d = 0; d < 64; ++d) dn += h2f(Qs[tid][d]) * kss[d];
        for (int s = 0; s <= tid; ++s) dn += h2f(Sch[tid][s]);
        den[tid] = 1.0f / fmaxf(dn, 1e-6f);
    }
    __syncthreads();

    // --- out = Sch @ V + Q @ KV ---
    f16x8 as0 = *(const f16x8*)&Sch[w * 16 + fr][quad * 8];
    f16x8 as1 = *(const f16x8*)&Sch[w * 16 + fr][32 + quad * 8];
    f32x4 oc[4];
#pragma unroll
    for (int j = 0; j < 4; ++j)
#pragma unroll
        for (int r = 0; r < 4; ++r) oc[j][r] = 0.0f;
#pragma unroll
    for (int j = 0; j < 4; ++j) {
        f16x8 b0 = *(const f16x8*)&Vt[j * 16 + fr][quad * 8];
        f16x8 b1 = *(const f16x8*)&Vt[j * 16 + fr][32 + quad * 8];
        oc[j] = __builtin_amdgcn_mfma_f32_16x16x32_f16(as0, b0, oc[j], 0, 0, 0);
        oc[j] = __builtin_amdgcn_mfma_f32_16x16x32_f16(as1, b1, oc[j], 0, 0, 0);
        f16x8 k0 = *(const f16x8*)&KVt[j * 16 + fr][quad * 8];
        f16x8 k1 = *(const f16x8*)&KVt[j * 16 + fr][32 + quad * 8];
        oc[j] = __builtin_amdgcn_mfma_f32_16x16x32_f16(aq0, k0, oc[j], 0, 0, 0);
        oc[j] = __builtin_amdgcn_mfma_f32_16x16x32_f16(aq1, k1, oc[j], 0, 0, 0);
    }
    // scale by 1/denom, store in place over q slice
#pragma unroll
    for (int j = 0; j < 4; ++j)
#pragma unroll
        for (int r = 0; r < 4; ++r) {
            int t = trow + r;
            qkv[base + (long)t * QKVC + j * 16 + fr] = f2h(oc[j][r] * den[t]);
        }
}

// ---------------------------------------------------------------------------
extern "C" void kernel_launch(void* const* d_in, const int* in_sizes, int n_in,
                              void* d_out, int out_size, void* d_ws, size_t ws_size,
                              hipStream_t stream)
{
    const float* x     = (const float*)d_in[0];
    const float* w_qkv = (const float*)d_in[1];
    const float* w_out = (const float*)d_in[2];
    float* out = (float*)d_out;

    // Workspace: qkv fp16 only (100.7 MB — proven-safe footprint).
    u16* qkv = (u16*)d_ws;
    // d_out doubles as scratch before the final GEMM writes it:
    u16* xf16  = (u16*)d_out;                         // 16384*1024 fp16
    u16* wqkvT = xf16 + (size_t)NTOK * DMODEL;        // 3072*1024 fp16
    u16* S     = (u16*)d_out;                         // 64*64*4096 fp16 (alias xf16)
    float* ksum = (float*)((char*)d_out + 33554432);  // 64*64*64 fp32 (alias wqkvT)
    // w_outT lives in the dead k-slice of qkv (rows 0..1023, cols 1024..2047)
    u16* woutT = qkv + 1024;                          // [n][k], row stride 3072

    dim3 blk(256);
    dim3 gblk(512);

    // 0) conversions for GEMM1
    convert_f32_f16<<<NTOK * DMODEL / 1024, blk, 0, stream>>>(x, xf16);
    transpose_convert<<<dim3(QKVC / 64, DMODEL / 64), blk, 0, stream>>>(
        w_qkv, QKVC, wqkvT, DMODEL);

    // 1) qkv = x @ w_qkv with fused RoPE+elu on q,k cols (MFMA fp16, 256² ring)
    gemm_mfma<u16, true><<<dim3(QKVC / 256, NTOK / 256), gblk, 0, stream>>>(
        xf16, DMODEL, wqkvT, DMODEL, qkv, QKVC, DMODEL);

    // 2) chunk-parallel linear attention (all MFMA)
    chunk_sums_mfma<<<64 * NCHUNK, blk, 0, stream>>>(qkv, S, ksum);
    scan_kernel<<<64 * 16, blk, 0, stream>>>(S, ksum);
    chunk_out_mfma<<<64 * NCHUNK, blk, 0, stream>>>(qkv, S, ksum);

    // 3) w_out transpose into dead k-slice, then out = attn @ w_out (MFMA)
    transpose_convert<<<dim3(DMODEL / 64, DMODEL / 64), blk, 0, stream>>>(
        w_out, DMODEL, woutT, QKVC);
    gemm_mfma<float, false><<<dim3(DMODEL / 256, NTOK / 256), gblk, 0, stream>>>(
        qkv, QKVC, woutT, QKVC, out, DMODEL, DMODEL);
}

// Round 4
// 353.660 us; speedup vs baseline: 1.2457x; 1.0083x over previous
//
#include <hip/hip_runtime.h>
#include <math.h>

// Problem constants
#define BATCH 4
#define SEQ   4096
#define DMODEL 1024
#define HEADS 16
#define HDIM  64
#define CHUNK 64
#define NCHUNK 64
#define NTOK  16384          // BATCH*SEQ
#define QKVC  3072           // 3*DMODEL
#define SCALE_F 0.35355339059327373f  // 64^-0.25
#define ROPE_K 0.4152410118609203f    // log2(10000)/32

typedef unsigned short u16;
typedef _Float16 f16;
typedef __attribute__((ext_vector_type(8))) f16 f16x8;
typedef __attribute__((ext_vector_type(4))) float f32x4;

__device__ __forceinline__ u16 f2h(float f) { f16 h = (f16)f; return *(u16*)&h; }
__device__ __forceinline__ float h2f(u16 u) { f16 h = *(f16*)&u; return (float)h; }
__device__ __forceinline__ void storeC(u16* p, float v) { *p = f2h(v); }
__device__ __forceinline__ void storeC(float* p, float v) { *p = v; }

// Async global->LDS, 16B per lane. LDS dest is wave-uniform base + lane*16.
__device__ __forceinline__ void gload_lds16(const u16* g, u16* l)
{
    __builtin_amdgcn_global_load_lds(
        (const __attribute__((address_space(1))) void*)g,
        (__attribute__((address_space(3))) void*)l, 16, 0, 0);
}

// ---------------------------------------------------------------------------
// fp32 -> fp16 flat convert (n multiple of 1024)
// ---------------------------------------------------------------------------
__global__ __launch_bounds__(256)
void convert_f32_f16(const float* __restrict__ src, u16* __restrict__ dst)
{
    long i = ((long)blockIdx.x * 256 + threadIdx.x) * 4;
    float4 v = *(const float4*)(src + i);
    ushort4 o; o.x = f2h(v.x); o.y = f2h(v.y); o.z = f2h(v.z); o.w = f2h(v.w);
    *(ushort4*)(dst + i) = o;
}

// ---------------------------------------------------------------------------
// Transpose + convert: src fp32 [R][C] -> dst fp16 [C][R], dst row stride dld.
// ---------------------------------------------------------------------------
__global__ __launch_bounds__(256)
void transpose_convert(const float* __restrict__ src, int C,
                       u16* __restrict__ dst, int dld)
{
    __shared__ u16 tile[64][72];
    const int r0 = blockIdx.y * 64, c0 = blockIdx.x * 64;
    const int t = threadIdx.x;
    const int rr = t >> 4, cc4 = (t & 15) * 4;
#pragma unroll
    for (int j = 0; j < 4; ++j) {
        int r = rr + j * 16;
        float4 v = *(const float4*)(src + (long)(r0 + r) * C + c0 + cc4);
        tile[cc4 + 0][r] = f2h(v.x);
        tile[cc4 + 1][r] = f2h(v.y);
        tile[cc4 + 2][r] = f2h(v.z);
        tile[cc4 + 3][r] = f2h(v.w);
    }
    __syncthreads();
#pragma unroll
    for (int j = 0; j < 4; ++j) {
        int c = rr + j * 16;
        ushort4 o = *(ushort4*)&tile[c][cc4];
        *(ushort4*)(dst + (long)(c0 + c) * dld + r0 + cc4) = o;
    }
}

// ---------------------------------------------------------------------------
// MFMA fp16 GEMM: C[M,N] = A[M,K] @ B[K,N], B given TRANSPOSED (BT[N][K]).
// 256x256 tile, 8 waves (2Mx4N, 128x64/wave), ring of 4 K=32 slots, depth-3
// prefetch, ONE barrier + counted vmcnt per K-half (never 0 in steady state).
// ROLE-SKEW: waves 0-3 (wm=0) and 4-7 (wm=1) issue the same per-window
// instruction multiset in opposite order (MFMA-first vs reads-first), so the
// two waves sharing each SIMD keep the MFMA and LDS pipes co-busy instead of
// phase-aligned-serial. Hazard structure identical per wave: same barrier
// count/sequence, same gload issue order (same vmcnt ladder), all slot
// reads drained by lgkmcnt(0) before the barrier preceding any re-stage.
// T2 slot-XOR swizzle (measured 0 conflicts), T5 setprio around MFMA.
// ROPE=true: fused RoPE + elu(x*SCALE)+1 epilogue on cols < 2048 (q,k).
// ---------------------------------------------------------------------------
template <typename CT, bool ROPE>
__global__ __launch_bounds__(512, 2)
void gemm_mfma(const u16* __restrict__ A, int lda,
               const u16* __restrict__ BT, int ldbt,
               CT* __restrict__ C, int ldc, int K)
{
    // 4 ring slots x (A 256x32 + B 256x32) u16 = 4 x 32 KB = 128 KiB
    __shared__ u16 ringA[4][256 * 32];
    __shared__ u16 ringB[4][256 * 32];

    const int tid = threadIdx.x;
    const long m0 = (long)blockIdx.y * 256, n0 = (long)blockIdx.x * 256;
    const int w = tid >> 6, lane = tid & 63;
    const int wm = w >> 2, wn = w & 3;           // 2 x 4 wave grid
    const int fr = lane & 15, quad = lane >> 4;
    // swizzled 16B-slot offset for fragment reads (u16 units):
    // slot' = quad ^ ((row>>1)&3); row within 16-aligned base -> fr
    const int sw = (quad ^ ((fr >> 1) & 3)) * 8;

    // Staging source map: one gload = 512 thr x 16B = 8 KB = 128 rows of 64B.
    // LDS chunk c = tid: row = c>>2, slot = c&3; inverse-swizzled source col.
    const int srow = tid >> 2;
    const int scol = ((tid & 3) ^ ((tid >> 3) & 3)) * 8;
    const u16* ga = A  + (m0 + srow) * (long)lda  + scol;
    const u16* gb = BT + (n0 + srow) * (long)ldbt + scol;
    const long a128 = 128 * (long)lda, b128 = 128 * (long)ldbt;

    f32x4 acc[8][4];
#pragma unroll
    for (int i = 0; i < 8; ++i)
#pragma unroll
        for (int j = 0; j < 4; ++j)
#pragma unroll
            for (int r = 0; r < 4; ++r) acc[i][j][r] = 0.0f;

    // stage halves of one K-slot (2 gloads each -> vmcnt += 2)
    auto STAGE_A = [&](int h) {
        u16* la = &ringA[h & 3][w * 512];
        const long ko = (long)h << 5;
        gload_lds16(ga + ko,        la);
        gload_lds16(ga + ko + a128, la + 4096);
    };
    auto STAGE_B = [&](int h) {
        u16* lb = &ringB[h & 3][w * 512];
        const long ko = (long)h << 5;
        gload_lds16(gb + ko,        lb);
        gload_lds16(gb + ko + b128, lb + 4096);
    };
    // fragment read helpers
    auto RD_A = [&](const u16* As_, int mi) -> f16x8 {
        return *(const f16x8*)&As_[(wm * 128 + mi * 16 + fr) * 32 + sw];
    };
    auto RD_B = [&](const u16* Bs_, int nj) -> f16x8 {
        return *(const f16x8*)&Bs_[(wn * 64 + nj * 16 + fr) * 32 + sw];
    };

    // prologue: stage slots 0..2 (12 gloads), validate slot 0
    STAGE_A(0); STAGE_B(0);
    STAGE_A(1); STAGE_B(1);
    STAGE_A(2); STAGE_B(2);
    asm volatile("s_waitcnt vmcnt(8)" ::: "memory");   // slot 0 landed (mine)
    __builtin_amdgcn_s_barrier();                      // slot 0 valid block-wide

    const int NH = K >> 5;                             // 32 for K=1024

    if (wm == 0) {
        // ---- role A: MFMA-first window ----
        // [MFMA1(h-1) | reads(h)+STAGE_A | MFMA0(h) | af1+STAGE_B | waits|bar]
        for (int h = 0; h < NH; ++h) {
            const u16* As_ = ringA[h & 3];
            const u16* Bs_ = ringB[h & 3];
            f16x8 af0[4], af1[4], bf[4];
#pragma unroll
            for (int mi = 0; mi < 4; ++mi) af0[mi] = RD_A(As_, mi);
#pragma unroll
            for (int nj = 0; nj < 4; ++nj) bf[nj] = RD_B(Bs_, nj);
            if (h < NH - 3) STAGE_A(h + 3);

            __builtin_amdgcn_s_setprio(1);
#pragma unroll
            for (int mi = 0; mi < 4; ++mi)
#pragma unroll
                for (int nj = 0; nj < 4; ++nj)
                    acc[mi][nj] = __builtin_amdgcn_mfma_f32_16x16x32_f16(
                        af0[mi], bf[nj], acc[mi][nj], 0, 0, 0);
            __builtin_amdgcn_s_setprio(0);

#pragma unroll
            for (int mi = 0; mi < 4; ++mi) af1[mi] = RD_A(As_, mi + 4);
            if (h < NH - 3) STAGE_B(h + 3);

            if (h <= NH - 4) {
                asm volatile("s_waitcnt vmcnt(8)" ::: "memory");
            } else if (h == NH - 3) {
                asm volatile("s_waitcnt vmcnt(4)" ::: "memory");
            } else if (h == NH - 2) {
                asm volatile("s_waitcnt vmcnt(0)" ::: "memory");
            }
            if (h < NH - 1) {
                asm volatile("s_waitcnt lgkmcnt(0)" ::: "memory");
                __builtin_amdgcn_s_barrier();
            }

            __builtin_amdgcn_s_setprio(1);
#pragma unroll
            for (int mi = 0; mi < 4; ++mi)
#pragma unroll
                for (int nj = 0; nj < 4; ++nj)
                    acc[mi + 4][nj] = __builtin_amdgcn_mfma_f32_16x16x32_f16(
                        af1[mi], bf[nj], acc[mi + 4][nj], 0, 0, 0);
            __builtin_amdgcn_s_setprio(0);
        }
    } else {
        // ---- role B: reads-first window ----
        // [reads(h)+STAGE_A | af1+STAGE_B | MFMA0(h)+MFMA1(h) | waits | bar]
        for (int h = 0; h < NH; ++h) {
            const u16* As_ = ringA[h & 3];
            const u16* Bs_ = ringB[h & 3];
            f16x8 af0[4], af1[4], bf[4];
#pragma unroll
            for (int mi = 0; mi < 4; ++mi) af0[mi] = RD_A(As_, mi);
#pragma unroll
            for (int nj = 0; nj < 4; ++nj) bf[nj] = RD_B(Bs_, nj);
            if (h < NH - 3) STAGE_A(h + 3);
#pragma unroll
            for (int mi = 0; mi < 4; ++mi) af1[mi] = RD_A(As_, mi + 4);
            if (h < NH - 3) STAGE_B(h + 3);

            __builtin_amdgcn_s_setprio(1);
#pragma unroll
            for (int mi = 0; mi < 4; ++mi)
#pragma unroll
                for (int nj = 0; nj < 4; ++nj)
                    acc[mi][nj] = __builtin_amdgcn_mfma_f32_16x16x32_f16(
                        af0[mi], bf[nj], acc[mi][nj], 0, 0, 0);
#pragma unroll
            for (int mi = 0; mi < 4; ++mi)
#pragma unroll
                for (int nj = 0; nj < 4; ++nj)
                    acc[mi + 4][nj] = __builtin_amdgcn_mfma_f32_16x16x32_f16(
                        af1[mi], bf[nj], acc[mi + 4][nj], 0, 0, 0);
            __builtin_amdgcn_s_setprio(0);

            if (h <= NH - 4) {
                asm volatile("s_waitcnt vmcnt(8)" ::: "memory");
            } else if (h == NH - 3) {
                asm volatile("s_waitcnt vmcnt(4)" ::: "memory");
            } else if (h == NH - 2) {
                asm volatile("s_waitcnt vmcnt(0)" ::: "memory");
            }
            if (h < NH - 1) {
                asm volatile("s_waitcnt lgkmcnt(0)" ::: "memory");
                __builtin_amdgcn_s_barrier();
            }
        }
    }

    // C/D: col = lane&15 (+16*nj), row = quad*4 + r (+16*mi)
    const long cm = m0 + wm * 128 + quad * 4;
    const long cn = n0 + wn * 64 + fr;

    if (ROPE && cn < 2048) {
        // lane's 4 cols within its 64-aligned head: fr, fr+16, fr+32, fr+48.
        // rope pairs: (nj0,nj2) with d2=fr; (nj1,nj3) with d2=fr+16.
        const float invf0 = exp2f(-(float)fr * ROPE_K);
        const float invf1 = exp2f(-(float)(fr + 16) * ROPE_K);
#pragma unroll
        for (int mi = 0; mi < 8; ++mi)
#pragma unroll
            for (int r = 0; r < 4; ++r) {
                long row = cm + mi * 16 + r;
                float n = (float)(int)(row & (SEQ - 1));
                float s0, c0, s1, c1;
                __sincosf(n * invf0, &s0, &c0);
                __sincosf(n * invf1, &s1, &c1);
                float x1 = acc[mi][0][r], x2 = acc[mi][2][r];
                float x3 = acc[mi][1][r], x4 = acc[mi][3][r];
                float u1 = (x1 * c0 - x2 * s0) * SCALE_F;
                float u2 = (x1 * s0 + x2 * c0) * SCALE_F;
                float u3 = (x3 * c1 - x4 * s1) * SCALE_F;
                float u4 = (x3 * s1 + x4 * c1) * SCALE_F;
                u1 = (u1 > 0.0f) ? (u1 + 1.0f) : __expf(u1);
                u2 = (u2 > 0.0f) ? (u2 + 1.0f) : __expf(u2);
                u3 = (u3 > 0.0f) ? (u3 + 1.0f) : __expf(u3);
                u4 = (u4 > 0.0f) ? (u4 + 1.0f) : __expf(u4);
                CT* pr = C + row * ldc + cn;
                storeC(pr, u1); storeC(pr + 16, u3);
                storeC(pr + 32, u2); storeC(pr + 48, u4);
            }
    } else {
#pragma unroll
        for (int mi = 0; mi < 8; ++mi)
#pragma unroll
            for (int nj = 0; nj < 4; ++nj)
#pragma unroll
                for (int r = 0; r < 4; ++r)
                    storeC(&C[(cm + mi * 16 + r) * ldc + cn + nj * 16], acc[mi][nj][r]);
    }
}

// ---------------------------------------------------------------------------
// Per-(b,h,chunk): S[m][d] = sum_t V[t][m] K[t][d]  (= (K^T V)^T, fp16),
// ksum[d] = sum_t K[t][d] (fp32). MFMA 16x16x32.
// ---------------------------------------------------------------------------
__global__ __launch_bounds__(256)
void chunk_sums_mfma(const u16* __restrict__ qkv,
                     u16* __restrict__ S, float* __restrict__ ksum)
{
    __shared__ u16 Kt[64][72];   // [d][t]
    __shared__ u16 Vt[64][72];   // [m][t]

    const int blk = blockIdx.x;
    const int c = blk & 63, bh = blk >> 6;
    const int b = bh >> 4, h = bh & 15;
    const int tid = threadIdx.x;
    const long base = (long)(b * SEQ + c * CHUNK) * QKVC + h * HDIM;

#pragma unroll
    for (int j = 0; j < 4; ++j) {
        int i4 = (j * 256 + tid) * 4;
        int t = i4 >> 6, d = i4 & 63;
        const u16* src = qkv + base + (long)t * QKVC + d;
        ushort4 kk = *(const ushort4*)(src + DMODEL);
        ushort4 vv = *(const ushort4*)(src + 2 * DMODEL);
        Kt[d + 0][t] = kk.x; Kt[d + 1][t] = kk.y;
        Kt[d + 2][t] = kk.z; Kt[d + 3][t] = kk.w;
        Vt[d + 0][t] = vv.x; Vt[d + 1][t] = vv.y;
        Vt[d + 2][t] = vv.z; Vt[d + 3][t] = vv.w;
    }
    __syncthreads();

    const int w = tid >> 6, lane = tid & 63;
    const int fr = lane & 15, quad = lane >> 4;

    // D[m][d] = sum_t Vt[m][t] * K[t][d];  A = Vt, B-op layout [d][t] = Kt
    f16x8 af0 = *(const f16x8*)&Vt[w * 16 + fr][quad * 8];
    f16x8 af1 = *(const f16x8*)&Vt[w * 16 + fr][32 + quad * 8];
    f32x4 acc[4];
#pragma unroll
    for (int j = 0; j < 4; ++j)
#pragma unroll
        for (int r = 0; r < 4; ++r) acc[j][r] = 0.0f;
#pragma unroll
    for (int j = 0; j < 4; ++j) {
        f16x8 b0 = *(const f16x8*)&Kt[j * 16 + fr][quad * 8];
        f16x8 b1 = *(const f16x8*)&Kt[j * 16 + fr][32 + quad * 8];
        acc[j] = __builtin_amdgcn_mfma_f32_16x16x32_f16(af0, b0, acc[j], 0, 0, 0);
        acc[j] = __builtin_amdgcn_mfma_f32_16x16x32_f16(af1, b1, acc[j], 0, 0, 0);
    }
    const long sb = (long)blk * 4096;
    const int mrow = w * 16 + quad * 4;
#pragma unroll
    for (int j = 0; j < 4; ++j)
#pragma unroll
        for (int r = 0; r < 4; ++r)
            S[sb + (mrow + r) * 64 + j * 16 + fr] = f2h(acc[j][r]);

    if (tid < 64) {
        float s = 0.0f;
        for (int t = 0; t < 64; ++t) s += h2f(Kt[tid][t]);
        ksum[(long)blk * 64 + tid] = s;
    }
}

// ---------------------------------------------------------------------------
// Exclusive prefix scan over chunks (per bh): S (fp16) and ksum (fp32).
// ---------------------------------------------------------------------------
__global__ __launch_bounds__(256)
void scan_kernel(u16* __restrict__ S, float* __restrict__ ksum)
{
    const int blk = blockIdx.x;
    const int slice = blk & 15, bh = blk >> 4;
    const int p = slice * 256 + threadIdx.x;
    const long base = (long)bh * NCHUNK * 4096 + p;
    float acc = 0.0f;
    for (int c = 0; c < NCHUNK; ++c) {
        long idx = base + (long)c * 4096;
        float tmp = h2f(S[idx]);
        S[idx] = f2h(acc);
        acc += tmp;
    }
    if (slice == 0 && threadIdx.x < 64) {
        const long kb = (long)bh * NCHUNK * 64 + threadIdx.x;
        float ka = 0.0f;
        for (int c = 0; c < NCHUNK; ++c) {
            float t = ksum[kb + (long)c * 64];
            ksum[kb + (long)c * 64] = ka;
            ka += t;
        }
    }
}

// ---------------------------------------------------------------------------
// Per-(b,h,chunk) output via MFMA:
//   Sc = causal(Q K^T); out = Sc @ V + Q @ KV_prefix; out /= denom.
// In place over the q slice. S holds KV^T prefix ([m][d]).
// ---------------------------------------------------------------------------
__global__ __launch_bounds__(256)
void chunk_out_mfma(u16* __restrict__ qkv,
                    const u16* __restrict__ S, const float* __restrict__ ksum)
{
    __shared__ u16 Qs[64][72];    // [t][d]
    __shared__ u16 Ks[64][72];    // [s][d]  (B-op for QK^T)
    __shared__ u16 Vt[64][72];    // [m][s]  (B-op for Sc@V)
    __shared__ u16 KVt[64][72];   // [m][d]  (B-op for Q@KV)
    __shared__ u16 Sch[64][72];   // [t][s]  masked scores (A-op for Sc@V)
    __shared__ float kss[64];
    __shared__ float den[64];

    const int blk = blockIdx.x;
    const int c = blk & 63, bh = blk >> 6;
    const int b = bh >> 4, h = bh & 15;
    const int tid = threadIdx.x;
    const long base = (long)(b * SEQ + c * CHUNK) * QKVC + h * HDIM;

#pragma unroll
    for (int j = 0; j < 4; ++j) {
        int i4 = (j * 256 + tid) * 4;
        int t = i4 >> 6, d = i4 & 63;
        const u16* src = qkv + base + (long)t * QKVC + d;
        *(ushort4*)&Qs[t][d] = *(const ushort4*)(src);
        *(ushort4*)&Ks[t][d] = *(const ushort4*)(src + DMODEL);
        ushort4 vv = *(const ushort4*)(src + 2 * DMODEL);
        Vt[d + 0][t] = vv.x; Vt[d + 1][t] = vv.y;
        Vt[d + 2][t] = vv.z; Vt[d + 3][t] = vv.w;
        *(ushort4*)&KVt[t][d] = *(const ushort4*)(S + (long)blk * 4096 + i4);
    }
    if (tid < 64) kss[tid] = ksum[(long)blk * 64 + tid];
    __syncthreads();

    const int w = tid >> 6, lane = tid & 63;
    const int fr = lane & 15, quad = lane >> 4;
    const int trow = w * 16 + quad * 4;   // C-layout row base

    // --- Sc = Q K^T (wave w: rows w*16..+16) ---
    f16x8 aq0 = *(const f16x8*)&Qs[w * 16 + fr][quad * 8];
    f16x8 aq1 = *(const f16x8*)&Qs[w * 16 + fr][32 + quad * 8];
    f32x4 sc[4];
#pragma unroll
    for (int j = 0; j < 4; ++j)
#pragma unroll
        for (int r = 0; r < 4; ++r) sc[j][r] = 0.0f;
#pragma unroll
    for (int j = 0; j < 4; ++j) {
        f16x8 b0 = *(const f16x8*)&Ks[j * 16 + fr][quad * 8];
        f16x8 b1 = *(const f16x8*)&Ks[j * 16 + fr][32 + quad * 8];
        sc[j] = __builtin_amdgcn_mfma_f32_16x16x32_f16(aq0, b0, sc[j], 0, 0, 0);
        sc[j] = __builtin_amdgcn_mfma_f32_16x16x32_f16(aq1, b1, sc[j], 0, 0, 0);
    }
    // causal mask + store fp16
#pragma unroll
    for (int j = 0; j < 4; ++j)
#pragma unroll
        for (int r = 0; r < 4; ++r) {
            int t = trow + r, s = j * 16 + fr;
            Sch[t][s] = f2h(s <= t ? sc[j][r] : 0.0f);
        }
    __syncthreads();

    // --- denominators ---
    if (tid < 64) {
        float dn = 0.0f;
        for (int d = 0; d < 64; ++d) dn += h2f(Qs[tid][d]) * kss[d];
        for (int s = 0; s <= tid; ++s) dn += h2f(Sch[tid][s]);
        den[tid] = 1.0f / fmaxf(dn, 1e-6f);
    }
    __syncthreads();

    // --- out = Sch @ V + Q @ KV ---
    f16x8 as0 = *(const f16x8*)&Sch[w * 16 + fr][quad * 8];
    f16x8 as1 = *(const f16x8*)&Sch[w * 16 + fr][32 + quad * 8];
    f32x4 oc[4];
#pragma unroll
    for (int j = 0; j < 4; ++j)
#pragma unroll
        for (int r = 0; r < 4; ++r) oc[j][r] = 0.0f;
#pragma unroll
    for (int j = 0; j < 4; ++j) {
        f16x8 b0 = *(const f16x8*)&Vt[j * 16 + fr][quad * 8];
        f16x8 b1 = *(const f16x8*)&Vt[j * 16 + fr][32 + quad * 8];
        oc[j] = __builtin_amdgcn_mfma_f32_16x16x32_f16(as0, b0, oc[j], 0, 0, 0);
        oc[j] = __builtin_amdgcn_mfma_f32_16x16x32_f16(as1, b1, oc[j], 0, 0, 0);
        f16x8 k0 = *(const f16x8*)&KVt[j * 16 + fr][quad * 8];
        f16x8 k1 = *(const f16x8*)&KVt[j * 16 + fr][32 + quad * 8];
        oc[j] = __builtin_amdgcn_mfma_f32_16x16x32_f16(aq0, k0, oc[j], 0, 0, 0);
        oc[j] = __builtin_amdgcn_mfma_f32_16x16x32_f16(aq1, k1, oc[j], 0, 0, 0);
    }
    // scale by 1/denom, store in place over q slice
#pragma unroll
    for (int j = 0; j < 4; ++j)
#pragma unroll
        for (int r = 0; r < 4; ++r) {
            int t = trow + r;
            qkv[base + (long)t * QKVC + j * 16 + fr] = f2h(oc[j][r] * den[t]);
        }
}

// ---------------------------------------------------------------------------
extern "C" void kernel_launch(void* const* d_in, const int* in_sizes, int n_in,
                              void* d_out, int out_size, void* d_ws, size_t ws_size,
                              hipStream_t stream)
{
    const float* x     = (const float*)d_in[0];
    const float* w_qkv = (const float*)d_in[1];
    const float* w_out = (const float*)d_in[2];
    float* out = (float*)d_out;

    // Workspace: qkv fp16 only (100.7 MB — proven-safe footprint).
    u16* qkv = (u16*)d_ws;
    // d_out doubles as scratch before the final GEMM writes it:
    u16* xf16  = (u16*)d_out;                         // 16384*1024 fp16
    u16* wqkvT = xf16 + (size_t)NTOK * DMODEL;        // 3072*1024 fp16
    u16* S     = (u16*)d_out;                         // 64*64*4096 fp16 (alias xf16)
    float* ksum = (float*)((char*)d_out + 33554432);  // 64*64*64 fp32 (alias wqkvT)
    // w_outT lives in the dead k-slice of qkv (rows 0..1023, cols 1024..2047)
    u16* woutT = qkv + 1024;                          // [n][k], row stride 3072

    dim3 blk(256);
    dim3 gblk(512);

    // 0) conversions for GEMM1
    convert_f32_f16<<<NTOK * DMODEL / 1024, blk, 0, stream>>>(x, xf16);
    transpose_convert<<<dim3(QKVC / 64, DMODEL / 64), blk, 0, stream>>>(
        w_qkv, QKVC, wqkvT, DMODEL);

    // 1) qkv = x @ w_qkv with fused RoPE+elu on q,k cols (MFMA fp16, 256² ring)
    gemm_mfma<u16, true><<<dim3(QKVC / 256, NTOK / 256), gblk, 0, stream>>>(
        xf16, DMODEL, wqkvT, DMODEL, qkv, QKVC, DMODEL);

    // 2) chunk-parallel linear attention (all MFMA)
    chunk_sums_mfma<<<64 * NCHUNK, blk, 0, stream>>>(qkv, S, ksum);
    scan_kernel<<<64 * 16, blk, 0, stream>>>(S, ksum);
    chunk_out_mfma<<<64 * NCHUNK, blk, 0, stream>>>(qkv, S, ksum);

    // 3) w_out transpose into dead k-slice, then out = attn @ w_out (MFMA)
    transpose_convert<<<dim3(DMODEL / 64, DMODEL / 64), blk, 0, stream>>>(
        w_out, DMODEL, woutT, QKVC);
    gemm_mfma<float, false><<<dim3(DMODEL / 256, NTOK / 256), gblk, 0, stream>>>(
        qkv, QKVC, woutT, QKVC, out, DMODEL, DMODEL);
}

// Round 5
// 341.550 us; speedup vs baseline: 1.2899x; 1.0355x over previous
//
#include <hip/hip_runtime.h>
#include <math.h>

// Problem constants
#define BATCH 4
#define SEQ   4096
#define DMODEL 1024
#define HEADS 16
#define HDIM  64
#define CHUNK 64
#define NCHUNK 64
#define NTOK  16384          // BATCH*SEQ
#define QKVC  3072           // 3*DMODEL
#define SCALE_F 0.35355339059327373f  // 64^-0.25
#define ROPE_K 0.4152410118609203f    // log2(10000)/32

typedef unsigned short u16;
typedef _Float16 f16;
typedef __attribute__((ext_vector_type(8))) f16 f16x8;
typedef __attribute__((ext_vector_type(4))) float f32x4;

__device__ __forceinline__ u16 f2h(float f) { f16 h = (f16)f; return *(u16*)&h; }
__device__ __forceinline__ float h2f(u16 u) { f16 h = *(f16*)&u; return (float)h; }
__device__ __forceinline__ void storeC(u16* p, float v) { *p = f2h(v); }
__device__ __forceinline__ void storeC(float* p, float v) { *p = v; }

// Async global->LDS, 16B per lane. LDS dest is wave-uniform base + lane*16.
__device__ __forceinline__ void gload_lds16(const u16* g, u16* l)
{
    __builtin_amdgcn_global_load_lds(
        (const __attribute__((address_space(1))) void*)g,
        (__attribute__((address_space(3))) void*)l, 16, 0, 0);
}

// ---------------------------------------------------------------------------
// fp32 -> fp16 flat convert (n multiple of 1024)
// ---------------------------------------------------------------------------
__global__ __launch_bounds__(256)
void convert_f32_f16(const float* __restrict__ src, u16* __restrict__ dst)
{
    long i = ((long)blockIdx.x * 256 + threadIdx.x) * 4;
    float4 v = *(const float4*)(src + i);
    ushort4 o; o.x = f2h(v.x); o.y = f2h(v.y); o.z = f2h(v.z); o.w = f2h(v.w);
    *(ushort4*)(dst + i) = o;
}

// ---------------------------------------------------------------------------
// Transpose + convert: src fp32 [R][C] -> dst fp16 [C][R], dst row stride dld.
// ---------------------------------------------------------------------------
__global__ __launch_bounds__(256)
void transpose_convert(const float* __restrict__ src, int C,
                       u16* __restrict__ dst, int dld)
{
    __shared__ u16 tile[64][72];
    const int r0 = blockIdx.y * 64, c0 = blockIdx.x * 64;
    const int t = threadIdx.x;
    const int rr = t >> 4, cc4 = (t & 15) * 4;
#pragma unroll
    for (int j = 0; j < 4; ++j) {
        int r = rr + j * 16;
        float4 v = *(const float4*)(src + (long)(r0 + r) * C + c0 + cc4);
        tile[cc4 + 0][r] = f2h(v.x);
        tile[cc4 + 1][r] = f2h(v.y);
        tile[cc4 + 2][r] = f2h(v.z);
        tile[cc4 + 3][r] = f2h(v.w);
    }
    __syncthreads();
#pragma unroll
    for (int j = 0; j < 4; ++j) {
        int c = rr + j * 16;
        ushort4 o = *(ushort4*)&tile[c][cc4];
        *(ushort4*)(dst + (long)(c0 + c) * dld + r0 + cc4) = o;
    }
}

// ---------------------------------------------------------------------------
// MFMA fp16 GEMM: C[M,N] = A[M,K] @ B[K,N], B given TRANSPOSED (BT[N][K]).
// 256x256 tile, 8 waves (2Mx4N, 128x64/wave), ring of 4 K=32 slots, depth-3
// prefetch, ONE barrier + counted vmcnt per K-half (never 0 in steady state).
// T1 XCD-chunk swizzle: lid=(bid%8)*(nwg/8)+bid/8 so all blocks sharing an
// A-panel run on ONE XCD (L2 reuse instead of L3 cross-XCD duplication).
// T2 slot-XOR swizzle (measured 0 conflicts), T5 setprio around MFMA.
// ROPE=true: fused RoPE + elu(x*SCALE)+1 epilogue on cols < 2048 (q,k).
// ---------------------------------------------------------------------------
template <typename CT, bool ROPE>
__global__ __launch_bounds__(512, 2)
void gemm_mfma(const u16* __restrict__ A, int lda,
               const u16* __restrict__ BT, int ldbt,
               CT* __restrict__ C, int ldc, int K)
{
    // 4 ring slots x (A 256x32 + B 256x32) u16 = 4 x 32 KB = 128 KiB
    __shared__ u16 ringA[4][256 * 32];
    __shared__ u16 ringB[4][256 * 32];

    const int tid = threadIdx.x;
    // --- T1: XCD-aware block swizzle (bijective; nwg % 8 == 0 here) ---
    const int gx = gridDim.x;
    const int nwg = gx * gridDim.y;
    const int bid = blockIdx.y * gx + blockIdx.x;        // dispatch-linear
    const int lid = (nwg & 7) ? bid
                              : (bid & 7) * (nwg >> 3) + (bid >> 3);
    const long m0 = (long)(lid / gx) * 256;
    const long n0 = (long)(lid % gx) * 256;

    const int w = tid >> 6, lane = tid & 63;
    const int wm = w >> 2, wn = w & 3;           // 2 x 4 wave grid
    const int fr = lane & 15, quad = lane >> 4;
    // swizzled 16B-slot offset for fragment reads (u16 units):
    // slot' = quad ^ ((row>>1)&3); row within 16-aligned base -> fr
    const int sw = (quad ^ ((fr >> 1) & 3)) * 8;

    // Staging source map: one gload = 512 thr x 16B = 8 KB = 128 rows of 64B.
    // LDS chunk c = tid: row = c>>2, slot = c&3; inverse-swizzled source col.
    const int srow = tid >> 2;
    const int scol = ((tid & 3) ^ ((tid >> 3) & 3)) * 8;
    const u16* ga = A  + (m0 + srow) * (long)lda  + scol;
    const u16* gb = BT + (n0 + srow) * (long)ldbt + scol;
    const long a128 = 128 * (long)lda, b128 = 128 * (long)ldbt;

    f32x4 acc[8][4];
#pragma unroll
    for (int i = 0; i < 8; ++i)
#pragma unroll
        for (int j = 0; j < 4; ++j)
#pragma unroll
            for (int r = 0; r < 4; ++r) acc[i][j][r] = 0.0f;

    // stage halves of one K-slot (2 gloads each -> vmcnt += 2)
    auto STAGE_A = [&](int h) {
        u16* la = &ringA[h & 3][w * 512];
        const long ko = (long)h << 5;
        gload_lds16(ga + ko,        la);
        gload_lds16(ga + ko + a128, la + 4096);
    };
    auto STAGE_B = [&](int h) {
        u16* lb = &ringB[h & 3][w * 512];
        const long ko = (long)h << 5;
        gload_lds16(gb + ko,        lb);
        gload_lds16(gb + ko + b128, lb + 4096);
    };

    // prologue: stage slots 0..2 (12 gloads), validate slot 0
    STAGE_A(0); STAGE_B(0);
    STAGE_A(1); STAGE_B(1);
    STAGE_A(2); STAGE_B(2);
    asm volatile("s_waitcnt vmcnt(8)" ::: "memory");   // slot 0 landed (mine)
    __builtin_amdgcn_s_barrier();                      // slot 0 valid block-wide

    const int NH = K >> 5;                             // 32 for K=1024
    for (int h = 0; h < NH; ++h) {
        const u16* As_ = ringA[h & 3];
        const u16* Bs_ = ringB[h & 3];
        f16x8 af0[4], af1[4], bf[4];

        // --- window top: reads for this slot + stage A-half of h+3 ---
#pragma unroll
        for (int mi = 0; mi < 4; ++mi)
            af0[mi] = *(const f16x8*)&As_[(wm * 128 + mi * 16 + fr) * 32 + sw];
#pragma unroll
        for (int nj = 0; nj < 4; ++nj)
            bf[nj] = *(const f16x8*)&Bs_[(wn * 64 + nj * 16 + fr) * 32 + sw];
        if (h < NH - 3) STAGE_A(h + 3);   // writes slot (h-1)&3: reads drained at B(h-1)

        // --- MFMA cluster 0 (mi 0..3) ---
        __builtin_amdgcn_s_setprio(1);
#pragma unroll
        for (int mi = 0; mi < 4; ++mi)
#pragma unroll
            for (int nj = 0; nj < 4; ++nj)
                acc[mi][nj] = __builtin_amdgcn_mfma_f32_16x16x32_f16(
                    af0[mi], bf[nj], acc[mi][nj], 0, 0, 0);
        __builtin_amdgcn_s_setprio(0);

        // --- second half reads + stage B-half of h+3 ---
#pragma unroll
        for (int mi = 0; mi < 4; ++mi)
            af1[mi] = *(const f16x8*)&As_[(wm * 128 + (mi + 4) * 16 + fr) * 32 + sw];
        if (h < NH - 3) STAGE_B(h + 3);

        // --- single sync point per slot: validate slot h+1, fence reads ---
        if (h <= NH - 4) {
            asm volatile("s_waitcnt vmcnt(8)" ::: "memory");   // slot h+1 landed
        } else if (h == NH - 3) {
            asm volatile("s_waitcnt vmcnt(4)" ::: "memory");
        } else if (h == NH - 2) {
            asm volatile("s_waitcnt vmcnt(0)" ::: "memory");
        }
        if (h < NH - 1) {
            asm volatile("s_waitcnt lgkmcnt(0)" ::: "memory"); // my slot-h reads done
            __builtin_amdgcn_s_barrier();                      // block-wide rendezvous
        }

        // --- MFMA cluster 1 (mi 4..7, operands pre-drained) ---
        __builtin_amdgcn_s_setprio(1);
#pragma unroll
        for (int mi = 0; mi < 4; ++mi)
#pragma unroll
            for (int nj = 0; nj < 4; ++nj)
                acc[mi + 4][nj] = __builtin_amdgcn_mfma_f32_16x16x32_f16(
                    af1[mi], bf[nj], acc[mi + 4][nj], 0, 0, 0);
        __builtin_amdgcn_s_setprio(0);
    }

    // C/D: col = lane&15 (+16*nj), row = quad*4 + r (+16*mi)
    const long cm = m0 + wm * 128 + quad * 4;
    const long cn = n0 + wn * 64 + fr;

    if (ROPE && cn < 2048) {
        // lane's 4 cols within its 64-aligned head: fr, fr+16, fr+32, fr+48.
        // rope pairs: (nj0,nj2) with d2=fr; (nj1,nj3) with d2=fr+16.
        const float invf0 = exp2f(-(float)fr * ROPE_K);
        const float invf1 = exp2f(-(float)(fr + 16) * ROPE_K);
#pragma unroll
        for (int mi = 0; mi < 8; ++mi)
#pragma unroll
            for (int r = 0; r < 4; ++r) {
                long row = cm + mi * 16 + r;
                float n = (float)(int)(row & (SEQ - 1));
                float s0, c0, s1, c1;
                __sincosf(n * invf0, &s0, &c0);
                __sincosf(n * invf1, &s1, &c1);
                float x1 = acc[mi][0][r], x2 = acc[mi][2][r];
                float x3 = acc[mi][1][r], x4 = acc[mi][3][r];
                float u1 = (x1 * c0 - x2 * s0) * SCALE_F;
                float u2 = (x1 * s0 + x2 * c0) * SCALE_F;
                float u3 = (x3 * c1 - x4 * s1) * SCALE_F;
                float u4 = (x3 * s1 + x4 * c1) * SCALE_F;
                u1 = (u1 > 0.0f) ? (u1 + 1.0f) : __expf(u1);
                u2 = (u2 > 0.0f) ? (u2 + 1.0f) : __expf(u2);
                u3 = (u3 > 0.0f) ? (u3 + 1.0f) : __expf(u3);
                u4 = (u4 > 0.0f) ? (u4 + 1.0f) : __expf(u4);
                CT* pr = C + row * ldc + cn;
                storeC(pr, u1); storeC(pr + 16, u3);
                storeC(pr + 32, u2); storeC(pr + 48, u4);
            }
    } else {
#pragma unroll
        for (int mi = 0; mi < 8; ++mi)
#pragma unroll
            for (int nj = 0; nj < 4; ++nj)
#pragma unroll
                for (int r = 0; r < 4; ++r)
                    storeC(&C[(cm + mi * 16 + r) * ldc + cn + nj * 16], acc[mi][nj][r]);
    }
}

// ---------------------------------------------------------------------------
// Per-(b,h,chunk): S[m][d] = sum_t V[t][m] K[t][d]  (= (K^T V)^T, fp16),
// ksum[d] = sum_t K[t][d] (fp32). MFMA 16x16x32.
// ---------------------------------------------------------------------------
__global__ __launch_bounds__(256)
void chunk_sums_mfma(const u16* __restrict__ qkv,
                     u16* __restrict__ S, float* __restrict__ ksum)
{
    __shared__ u16 Kt[64][72];   // [d][t]
    __shared__ u16 Vt[64][72];   // [m][t]

    const int blk = blockIdx.x;
    const int c = blk & 63, bh = blk >> 6;
    const int b = bh >> 4, h = bh & 15;
    const int tid = threadIdx.x;
    const long base = (long)(b * SEQ + c * CHUNK) * QKVC + h * HDIM;

#pragma unroll
    for (int j = 0; j < 4; ++j) {
        int i4 = (j * 256 + tid) * 4;
        int t = i4 >> 6, d = i4 & 63;
        const u16* src = qkv + base + (long)t * QKVC + d;
        ushort4 kk = *(const ushort4*)(src + DMODEL);
        ushort4 vv = *(const ushort4*)(src + 2 * DMODEL);
        Kt[d + 0][t] = kk.x; Kt[d + 1][t] = kk.y;
        Kt[d + 2][t] = kk.z; Kt[d + 3][t] = kk.w;
        Vt[d + 0][t] = vv.x; Vt[d + 1][t] = vv.y;
        Vt[d + 2][t] = vv.z; Vt[d + 3][t] = vv.w;
    }
    __syncthreads();

    const int w = tid >> 6, lane = tid & 63;
    const int fr = lane & 15, quad = lane >> 4;

    // D[m][d] = sum_t Vt[m][t] * K[t][d];  A = Vt, B-op layout [d][t] = Kt
    f16x8 af0 = *(const f16x8*)&Vt[w * 16 + fr][quad * 8];
    f16x8 af1 = *(const f16x8*)&Vt[w * 16 + fr][32 + quad * 8];
    f32x4 acc[4];
#pragma unroll
    for (int j = 0; j < 4; ++j)
#pragma unroll
        for (int r = 0; r < 4; ++r) acc[j][r] = 0.0f;
#pragma unroll
    for (int j = 0; j < 4; ++j) {
        f16x8 b0 = *(const f16x8*)&Kt[j * 16 + fr][quad * 8];
        f16x8 b1 = *(const f16x8*)&Kt[j * 16 + fr][32 + quad * 8];
        acc[j] = __builtin_amdgcn_mfma_f32_16x16x32_f16(af0, b0, acc[j], 0, 0, 0);
        acc[j] = __builtin_amdgcn_mfma_f32_16x16x32_f16(af1, b1, acc[j], 0, 0, 0);
    }
    const long sb = (long)blk * 4096;
    const int mrow = w * 16 + quad * 4;
#pragma unroll
    for (int j = 0; j < 4; ++j)
#pragma unroll
        for (int r = 0; r < 4; ++r)
            S[sb + (mrow + r) * 64 + j * 16 + fr] = f2h(acc[j][r]);

    if (tid < 64) {
        float s = 0.0f;
        for (int t = 0; t < 64; ++t) s += h2f(Kt[tid][t]);
        ksum[(long)blk * 64 + tid] = s;
    }
}

// ---------------------------------------------------------------------------
// Exclusive prefix scan over chunks (per bh): S (fp16) and ksum (fp32).
// ---------------------------------------------------------------------------
__global__ __launch_bounds__(256)
void scan_kernel(u16* __restrict__ S, float* __restrict__ ksum)
{
    const int blk = blockIdx.x;
    const int slice = blk & 15, bh = blk >> 4;
    const int p = slice * 256 + threadIdx.x;
    const long base = (long)bh * NCHUNK * 4096 + p;
    float acc = 0.0f;
    for (int c = 0; c < NCHUNK; ++c) {
        long idx = base + (long)c * 4096;
        float tmp = h2f(S[idx]);
        S[idx] = f2h(acc);
        acc += tmp;
    }
    if (slice == 0 && threadIdx.x < 64) {
        const long kb = (long)bh * NCHUNK * 64 + threadIdx.x;
        float ka = 0.0f;
        for (int c = 0; c < NCHUNK; ++c) {
            float t = ksum[kb + (long)c * 64];
            ksum[kb + (long)c * 64] = ka;
            ka += t;
        }
    }
}

// ---------------------------------------------------------------------------
// Per-(b,h,chunk) output via MFMA:
//   Sc = causal(Q K^T); out = Sc @ V + Q @ KV_prefix; out /= denom.
// In place over the q slice. S holds KV^T prefix ([m][d]).
// ---------------------------------------------------------------------------
__global__ __launch_bounds__(256)
void chunk_out_mfma(u16* __restrict__ qkv,
                    const u16* __restrict__ S, const float* __restrict__ ksum)
{
    __shared__ u16 Qs[64][72];    // [t][d]
    __shared__ u16 Ks[64][72];    // [s][d]  (B-op for QK^T)
    __shared__ u16 Vt[64][72];    // [m][s]  (B-op for Sc@V)
    __shared__ u16 KVt[64][72];   // [m][d]  (B-op for Q@KV)
    __shared__ u16 Sch[64][72];   // [t][s]  masked scores (A-op for Sc@V)
    __shared__ float kss[64];
    __shared__ float den[64];

    const int blk = blockIdx.x;
    const int c = blk & 63, bh = blk >> 6;
    const int b = bh >> 4, h = bh & 15;
    const int tid = threadIdx.x;
    const long base = (long)(b * SEQ + c * CHUNK) * QKVC + h * HDIM;

#pragma unroll
    for (int j = 0; j < 4; ++j) {
        int i4 = (j * 256 + tid) * 4;
        int t = i4 >> 6, d = i4 & 63;
        const u16* src = qkv + base + (long)t * QKVC + d;
        *(ushort4*)&Qs[t][d] = *(const ushort4*)(src);
        *(ushort4*)&Ks[t][d] = *(const ushort4*)(src + DMODEL);
        ushort4 vv = *(const ushort4*)(src + 2 * DMODEL);
        Vt[d + 0][t] = vv.x; Vt[d + 1][t] = vv.y;
        Vt[d + 2][t] = vv.z; Vt[d + 3][t] = vv.w;
        *(ushort4*)&KVt[t][d] = *(const ushort4*)(S + (long)blk * 4096 + i4);
    }
    if (tid < 64) kss[tid] = ksum[(long)blk * 64 + tid];
    __syncthreads();

    const int w = tid >> 6, lane = tid & 63;
    const int fr = lane & 15, quad = lane >> 4;
    const int trow = w * 16 + quad * 4;   // C-layout row base

    // --- Sc = Q K^T (wave w: rows w*16..+16) ---
    f16x8 aq0 = *(const f16x8*)&Qs[w * 16 + fr][quad * 8];
    f16x8 aq1 = *(const f16x8*)&Qs[w * 16 + fr][32 + quad * 8];
    f32x4 sc[4];
#pragma unroll
    for (int j = 0; j < 4; ++j)
#pragma unroll
        for (int r = 0; r < 4; ++r) sc[j][r] = 0.0f;
#pragma unroll
    for (int j = 0; j < 4; ++j) {
        f16x8 b0 = *(const f16x8*)&Ks[j * 16 + fr][quad * 8];
        f16x8 b1 = *(const f16x8*)&Ks[j * 16 + fr][32 + quad * 8];
        sc[j] = __builtin_amdgcn_mfma_f32_16x16x32_f16(aq0, b0, sc[j], 0, 0, 0);
        sc[j] = __builtin_amdgcn_mfma_f32_16x16x32_f16(aq1, b1, sc[j], 0, 0, 0);
    }
    // causal mask + store fp16
#pragma unroll
    for (int j = 0; j < 4; ++j)
#pragma unroll
        for (int r = 0; r < 4; ++r) {
            int t = trow + r, s = j * 16 + fr;
            Sch[t][s] = f2h(s <= t ? sc[j][r] : 0.0f);
        }
    __syncthreads();

    // --- denominators ---
    if (tid < 64) {
        float dn = 0.0f;
        for (int d = 0; d < 64; ++d) dn += h2f(Qs[tid][d]) * kss[d];
        for (int s = 0; s <= tid; ++s) dn += h2f(Sch[tid][s]);
        den[tid] = 1.0f / fmaxf(dn, 1e-6f);
    }
    __syncthreads();

    // --- out = Sch @ V + Q @ KV ---
    f16x8 as0 = *(const f16x8*)&Sch[w * 16 + fr][quad * 8];
    f16x8 as1 = *(const f16x8*)&Sch[w * 16 + fr][32 + quad * 8];
    f32x4 oc[4];
#pragma unroll
    for (int j = 0; j < 4; ++j)
#pragma unroll
        for (int r = 0; r < 4; ++r) oc[j][r] = 0.0f;
#pragma unroll
    for (int j = 0; j < 4; ++j) {
        f16x8 b0 = *(const f16x8*)&Vt[j * 16 + fr][quad * 8];
        f16x8 b1 = *(const f16x8*)&Vt[j * 16 + fr][32 + quad * 8];
        oc[j] = __builtin_amdgcn_mfma_f32_16x16x32_f16(as0, b0, oc[j], 0, 0, 0);
        oc[j] = __builtin_amdgcn_mfma_f32_16x16x32_f16(as1, b1, oc[j], 0, 0, 0);
        f16x8 k0 = *(const f16x8*)&KVt[j * 16 + fr][quad * 8];
        f16x8 k1 = *(const f16x8*)&KVt[j * 16 + fr][32 + quad * 8];
        oc[j] = __builtin_amdgcn_mfma_f32_16x16x32_f16(aq0, k0, oc[j], 0, 0, 0);
        oc[j] = __builtin_amdgcn_mfma_f32_16x16x32_f16(aq1, k1, oc[j], 0, 0, 0);
    }
    // scale by 1/denom, store in place over q slice
#pragma unroll
    for (int j = 0; j < 4; ++j)
#pragma unroll
        for (int r = 0; r < 4; ++r) {
            int t = trow + r;
            qkv[base + (long)t * QKVC + j * 16 + fr] = f2h(oc[j][r] * den[t]);
        }
}

// ---------------------------------------------------------------------------
extern "C" void kernel_launch(void* const* d_in, const int* in_sizes, int n_in,
                              void* d_out, int out_size, void* d_ws, size_t ws_size,
                              hipStream_t stream)
{
    const float* x     = (const float*)d_in[0];
    const float* w_qkv = (const float*)d_in[1];
    const float* w_out = (const float*)d_in[2];
    float* out = (float*)d_out;

    // Workspace: qkv fp16 only (100.7 MB — proven-safe footprint).
    u16* qkv = (u16*)d_ws;
    // d_out doubles as scratch before the final GEMM writes it:
    u16* xf16  = (u16*)d_out;                         // 16384*1024 fp16
    u16* wqkvT = xf16 + (size_t)NTOK * DMODEL;        // 3072*1024 fp16
    u16* S     = (u16*)d_out;                         // 64*64*4096 fp16 (alias xf16)
    float* ksum = (float*)((char*)d_out + 33554432);  // 64*64*64 fp32 (alias wqkvT)
    // w_outT lives in the dead k-slice of qkv (rows 0..1023, cols 1024..2047)
    u16* woutT = qkv + 1024;                          // [n][k], row stride 3072

    dim3 blk(256);
    dim3 gblk(512);

    // 0) conversions for GEMM1
    convert_f32_f16<<<NTOK * DMODEL / 1024, blk, 0, stream>>>(x, xf16);
    transpose_convert<<<dim3(QKVC / 64, DMODEL / 64), blk, 0, stream>>>(
        w_qkv, QKVC, wqkvT, DMODEL);

    // 1) qkv = x @ w_qkv with fused RoPE+elu on q,k cols (MFMA fp16, 256² ring)
    gemm_mfma<u16, true><<<dim3(QKVC / 256, NTOK / 256), gblk, 0, stream>>>(
        xf16, DMODEL, wqkvT, DMODEL, qkv, QKVC, DMODEL);

    // 2) chunk-parallel linear attention (all MFMA)
    chunk_sums_mfma<<<64 * NCHUNK, blk, 0, stream>>>(qkv, S, ksum);
    scan_kernel<<<64 * 16, blk, 0, stream>>>(S, ksum);
    chunk_out_mfma<<<64 * NCHUNK, blk, 0, stream>>>(qkv, S, ksum);

    // 3) w_out transpose into dead k-slice, then out = attn @ w_out (MFMA)
    transpose_convert<<<dim3(DMODEL / 64, DMODEL / 64), blk, 0, stream>>>(
        w_out, DMODEL, woutT, QKVC);
    gemm_mfma<float, false><<<dim3(DMODEL / 256, NTOK / 256), gblk, 0, stream>>>(
        qkv, QKVC, woutT, QKVC, out, DMODEL, DMODEL);
}